// Round 5
// baseline (468.082 us; speedup 1.0000x reference)
//
#include <hip/hip_runtime.h>
#include <cstdint>

#define T_    15
#define C1    6
#define F1    30
#define THR1  15.0f
#define F2    250
#define THR2  10.0f
#define WP    80
#define NLOC  6400          // 80*80
#define KWTA  8
#define P2R   84
#define P2S   (84*84)       // padded pooled map (pad 1, rounded to 84 for float4 align)
#define POT_OFF 24000000    // d_out: [0,24M) spike2, [24M,48M) pot2, [48M,48M+24) winners
#define WIN_OFF 48000000
#define EPS1  1e-2f         // conv1 decision margin (>> worst-case MFMA error ~1e-4)
#define FIXCAP 65536

typedef unsigned long long u64;
typedef unsigned short u16;
typedef short s16x8 __attribute__((ext_vector_type(8)));
typedef float f32x4 __attribute__((ext_vector_type(4)));

static __device__ __forceinline__ u16 f2bf(float x) {      // RNE fp32->bf16
    unsigned u = __float_as_uint(x);
    return (u16)((u + 0x7FFF + ((u >> 16) & 1)) >> 16);
}
static __device__ __forceinline__ float bf2f(u16 h) {
    return __uint_as_float(((unsigned)h) << 16);
}

// ---------- weight prep: bf16x3 splits in MFMA A-frag layout (W2 and W1) ----------
// Wf2 elem E = (((s*9+g)*16 + ft)*64 + lane)*8 + j ; A[m=lane&15][k=(lane>>4)*8+j]
//   f = ft*16 + (lane&15), c = k, g = ky*3+kx. f>=250 / c>=30 zero-padded.
// Wf1 elem E = (((sp*7+s)*2 + ft)*64 + lane)*8 + j
//   f = ft*16 + (lane&15) (<30), kp = s*4 + (lane>>4) = ky*5+kx (<25), c = j (<6).
__global__ void k_wprep(const float* __restrict__ W2, const float* __restrict__ W1,
                        u16* __restrict__ Wf2, u16* __restrict__ Wf1) {
    int b = blockIdx.x;
    if (b < 864) {
        int E = b * 256 + threadIdx.x;                   // 221,184 exact
        int j    = E & 7;
        int lane = (E >> 3) & 63;
        int ft   = (E >> 9) & 15;
        int rest = E >> 13;                              // 0..26
        int s = rest / 9, g = rest % 9;
        int c = (lane >> 4) * 8 + j;
        int f = ft * 16 + (lane & 15);
        float w = (c < F1 && f < F2) ? W2[f * 270 + c * 9 + g] : 0.f;
        u16 h = f2bf(w);          float fh = bf2f(h);
        u16 m = f2bf(w - fh);     float fm = bf2f(m);
        u16 l = f2bf(w - fh - fm);
        Wf2[E] = (s == 0) ? h : (s == 1) ? m : l;
    } else {
        int E = (b - 864) * 256 + threadIdx.x;           // 21,504 exact
        int j    = E & 7;
        int lane = (E >> 3) & 63;
        int ft   = (E >> 9) & 1;
        int sf   = E >> 10;                              // 0..20
        int s = sf % 7, sp = sf / 7;
        int q = lane >> 4, m15 = lane & 15;
        int f  = ft * 16 + m15;
        int kp = s * 4 + q;
        int c  = j;
        float w = 0.f;
        if (f < F1 && kp < 25 && c < C1) {
            int ky = kp / 5, kx = kp % 5;
            w = W1[((f * C1 + c) * 5 + ky) * 5 + kx];
        }
        u16 h = f2bf(w);          float fh = bf2f(h);
        u16 m = f2bf(w - fh);     float fm = bf2f(m);
        u16 l = f2bf(w - fh - fm);
        Wf1[E] = (sp == 0) ? h : (sp == 1) ? m : l;
    }
}

// ---------- conv1 via MFMA (bf16x3) + fire(15) + 2x2 maxpool + margin flags ----------
// grid (100, 15): block tile = 16 y x 16 x conv outputs, all 32 f (30 real).
// wave wv: conv rows y0+wv*4..+3 (nt), cols x0..x0+15 (n).
// Cells with any |pot-15|<EPS1 are appended to the fixup list (recomputed exactly).
__global__ __launch_bounds__(256) void k_conv1m(const float* __restrict__ data,
                                                const u16* __restrict__ Wf1,
                                                float* __restrict__ P2,
                                                int* __restrict__ cnt,
                                                int* __restrict__ list) {
    __shared__ u16 strip[3200];                          // [20 r][20 col][8 c] bf16
    __shared__ unsigned char pooled[2048];               // [8 py][8 px][32 f]
    int tid  = threadIdx.x;
    int lane = tid & 63;
    int wv   = __builtin_amdgcn_readfirstlane(tid >> 6);
    int t    = blockIdx.y;
    int xt = blockIdx.x % 10, yt = blockIdx.x / 10;
    int x0 = xt * 16, y0 = yt * 16;

    // stage input rows y0-2..y0+17, cols x0-2..x0+17 (bounds-checked virtual pad)
    for (int e = tid; e < 3200; e += 256) {              // e = (c*20 + r)*20 + cl
        int c = e / 400, r = (e / 20) % 20, cl = e % 20;
        int yy = y0 + r - 2, xx = x0 + cl - 2;
        float v = 0.f;
        if (c < C1 && yy >= 0 && yy < 160 && xx >= 0 && xx < 160)
            v = data[(size_t)(t * C1 + c) * 25600 + yy * 160 + xx];
        strip[(r * 20 + cl) * 8 + c] = f2bf(v);
    }
    __syncthreads();

    int q = lane >> 4, n = lane & 15;
    f32x4 acc[2][4];
    #pragma unroll
    for (int j = 0; j < 2; j++)
        #pragma unroll
        for (int nt = 0; nt < 4; nt++) acc[j][nt] = (f32x4)0.f;

    #pragma unroll
    for (int s = 0; s < 7; s++) {
        int kp = s * 4 + q;
        int ky = 0, kx = 0;
        if (kp < 25) { ky = kp / 5; kx = kp - ky * 5; }  // kp>=25: zero weights, read (0,0)
        s16x8 bf[4];
        #pragma unroll
        for (int nt = 0; nt < 4; nt++)
            bf[nt] = *(const s16x8*)&strip[((wv * 4 + nt + ky) * 20 + (n + kx)) * 8];
        #pragma unroll
        for (int sp = 0; sp < 3; sp++) {
            #pragma unroll
            for (int j = 0; j < 2; j++) {
                s16x8 af = *(const s16x8*)&Wf1[(size_t)(((sp * 7 + s) * 2 + j) * 64 + lane) * 8];
                #pragma unroll
                for (int nt = 0; nt < 4; nt++)
                    acc[j][nt] = __builtin_amdgcn_mfma_f32_16x16x32_bf16(af, bf[nt], acc[j][nt], 0, 0, 0);
            }
        }
    }

    // fire + flag; pool x via shfl_xor(1), y via nt pairs; even-n lanes own pooled px
    unsigned sb[4], nf[4];
    #pragma unroll
    for (int nt = 0; nt < 4; nt++) {
        unsigned s8 = 0, fl = 0;
        #pragma unroll
        for (int j = 0; j < 2; j++)
            #pragma unroll
            for (int r = 0; r < 4; r++) {
                float p = acc[j][nt][r];
                s8 |= (p > THR1 ? 1u : 0u) << (j * 4 + r);
                fl |= (fabsf(p - THR1) < EPS1 ? 1u : 0u);
            }
        sb[nt] = s8; nf[nt] = fl;
    }
    #pragma unroll
    for (int nt = 0; nt < 4; nt++) {
        sb[nt] |= (unsigned)__shfl_xor((int)sb[nt], 1, 64);
        nf[nt] |= (unsigned)__shfl_xor((int)nf[nt], 1, 64);
    }
    unsigned p0 = sb[0] | sb[1], p1 = sb[2] | sb[3];
    unsigned fw = (nf[0] | nf[1]) | ((nf[2] | nf[3]) << 1);
    fw |= (unsigned)__shfl_xor((int)fw, 16, 64);         // OR across q groups (dedupe)
    fw |= (unsigned)__shfl_xor((int)fw, 32, 64);
    if (!(n & 1)) {
        int px = n >> 1;
        #pragma unroll
        for (int j = 0; j < 2; j++)
            #pragma unroll
            for (int r = 0; r < 4; r++) {
                int f = j * 16 + q * 4 + r;
                pooled[((wv * 2 + 0) * 8 + px) * 32 + f] = (p0 >> (j * 4 + r)) & 1;
                pooled[((wv * 2 + 1) * 8 + px) * 32 + f] = (p1 >> (j * 4 + r)) & 1;
            }
        if (q == 0 && fw) {                              // one append per flagged cell
            int cb = t * NLOC + (yt * 8) * WP + (xt * 8 + px);
            if (fw & 1) { int id = atomicAdd(cnt, 1); if (id < FIXCAP) list[id] = cb + (wv * 2 + 0) * WP; }
            if (fw & 2) { int id = atomicAdd(cnt, 1); if (id < FIXCAP) list[id] = cb + (wv * 2 + 1) * WP; }
        }
    }
    __syncthreads();
    for (int i = tid; i < 1920; i += 256) {              // 30 f x 8 py x 8 px
        int f = i >> 6, pos = i & 63, py = pos >> 3, px = pos & 7;
        P2[(size_t)(t * F1 + f) * P2S + (size_t)(1 + yt * 8 + py) * P2R + (1 + xt * 8 + px)]
            = pooled[pos * 32 + f] ? 1.f : 0.f;
    }
}

// ---------- exact scalar recompute of flagged pooled cells (R3 fp32 c,ky,kx order) ----
__global__ void k_fix(const float* __restrict__ data, const float* __restrict__ W1,
                      float* __restrict__ P2, const int* __restrict__ list,
                      const int* __restrict__ cnt) {
    int m = *cnt; if (m > FIXCAP) m = FIXCAP;
    int nitems = m * F1;                                 // thread per (cell, f)
    for (int i = blockIdx.x * 256 + threadIdx.x; i < nitems; i += gridDim.x * 256) {
        int cell = list[i / F1], f = i % F1;
        int t = cell / NLOC, rem = cell % NLOC, py = rem / WP, px = rem % WP;
        bool s = false;
        #pragma unroll
        for (int dy = 0; dy < 2; dy++)
            #pragma unroll
            for (int dx = 0; dx < 2; dx++) {
                int y = 2 * py + dy, x = 2 * px + dx;    // conv output coords
                float acc = 0.f;
                for (int c = 0; c < C1; c++)
                    #pragma unroll
                    for (int ky = 0; ky < 5; ky++)
                        #pragma unroll
                        for (int kx = 0; kx < 5; kx++) {
                            int yy = y + ky - 2, xx = x + kx - 2;
                            float v = (yy >= 0 && yy < 160 && xx >= 0 && xx < 160)
                                ? data[(size_t)(t * C1 + c) * 25600 + yy * 160 + xx] : 0.f;
                            acc += W1[((f * C1 + c) * 5 + ky) * 5 + kx] * v;
                        }
                s |= acc > THR1;
            }
        P2[(size_t)(t * F1 + f) * P2S + (size_t)(1 + py) * P2R + (1 + px)] = s ? 1.f : 0.f;
    }
}

// ---------- conv2 via MFMA (bf16x3, R3 two-bank order) + fire + per-(t,loc) argmax ----
// grid (100, 15): block tile = 256 f x (4 rows x 16 cols). wave = 64 f x 64 locs.
__global__ __launch_bounds__(256) void k_conv2m(const float* __restrict__ P2,
                                                const u16* __restrict__ Wf,
                                                u64* __restrict__ gkey) {
    __shared__ u16 rawT[3456];                           // [6 r][4 q][18 col][8] bf16
    __shared__ u64 skey[256];                            // [wv][nt][n]
    int tid  = threadIdx.x;
    int lane = tid & 63;
    int wv   = __builtin_amdgcn_readfirstlane(tid >> 6);
    int t    = blockIdx.y;
    int xt = blockIdx.x % 5, yt = blockIdx.x / 5;
    int y0 = yt * 4, x0 = xt * 16;

    // stage strip rows y0..y0+5, cols x0..x0+17, 30ch (c-quad-major: 16B lane stride)
    for (int e = tid; e < 3456; e += 256) {              // e = (c*6 + r)*18 + col
        int c = e / 108, r = (e / 18) % 6, col = e % 18;
        float v = (c < F1)
            ? P2[(size_t)(t * F1 + c) * P2S + (size_t)(y0 + r) * P2R + (x0 + col)] : 0.f;
        rawT[((r * 4 + (c >> 3)) * 18 + col) * 8 + (c & 7)] = f2bf(v);
    }
    __syncthreads();

    int q = lane >> 4, n = lane & 15;
    f32x4 accA[4][4], accB[4][4];                        // [j(ftile)][nt]: hi | mid+lo
    #pragma unroll
    for (int j = 0; j < 4; j++)
        #pragma unroll
        for (int nt = 0; nt < 4; nt++) { accA[j][nt] = (f32x4)0.f; accB[j][nt] = (f32x4)0.f; }

    #pragma unroll
    for (int ky = 0; ky < 3; ky++) {
        #pragma unroll
        for (int kx = 0; kx < 3; kx++) {
            int g = ky * 3 + kx;
            s16x8 bf[4];
            #pragma unroll
            for (int nt = 0; nt < 4; nt++)
                bf[nt] = *(const s16x8*)&rawT[(((nt + ky) * 4 + q) * 18 + (n + kx)) * 8];
            #pragma unroll
            for (int s = 0; s < 3; s++) {
                #pragma unroll
                for (int j = 0; j < 4; j++) {
                    s16x8 af = *(const s16x8*)&Wf[(size_t)((((s * 9 + g) * 16) + (wv * 4 + j)) * 64 + lane) * 8];
                    if (s == 0) {
                        #pragma unroll
                        for (int nt = 0; nt < 4; nt++)
                            accA[j][nt] = __builtin_amdgcn_mfma_f32_16x16x32_bf16(af, bf[nt], accA[j][nt], 0, 0, 0);
                    } else {
                        #pragma unroll
                        for (int nt = 0; nt < 4; nt++)
                            accB[j][nt] = __builtin_amdgcn_mfma_f32_16x16x32_bf16(af, bf[nt], accB[j][nt], 0, 0, 0);
                    }
                }
            }
        }
    }

    // epilogue: fire + key(val, 255-f), reduce rows/lane, then q-lanes, then waves
    #pragma unroll
    for (int nt = 0; nt < 4; nt++) {
        u64 best = 0;
        #pragma unroll
        for (int j = 0; j < 4; j++) {
            #pragma unroll
            for (int r = 0; r < 4; r++) {
                float pot = accA[j][nt][r] + accB[j][nt][r];
                float rr  = pot > THR2 ? pot : 0.f;
                int f = (wv * 4 + j) * 16 + q * 4 + r;
                u64 key = ((u64)__float_as_uint(rr) << 32) | (u64)(unsigned)(255 - f);
                best = best > key ? best : key;
            }
        }
        u64 o = __shfl_xor(best, 16, 64); best = best > o ? best : o;
        o     = __shfl_xor(best, 32, 64); best = best > o ? best : o;
        if (q == 0) skey[(wv * 4 + nt) * 16 + n] = best;
    }
    __syncthreads();
    if (tid < 64) {
        int nt2 = tid >> 4, n2 = tid & 15;
        u64 bk = skey[nt2 * 16 + n2];
        #pragma unroll
        for (int w = 1; w < 4; w++) {
            u64 k = skey[(w * 4 + nt2) * 16 + n2];
            bk = bk > k ? bk : k;
        }
        gkey[(size_t)t * NLOC + (size_t)(y0 + nt2) * WP + (x0 + n2)] = bk;
    }
}

// ---------- per-(t,loc): winner logic + exact fp32 recompute of winner column ----------
__global__ void k_col(const u64* __restrict__ gkey, const float* __restrict__ P2,
                      const float* __restrict__ W2, int* __restrict__ winf,
                      float* __restrict__ colv) {
    int idx = blockIdx.x * 256 + threadIdx.x;            // 96,000 exact
    int t   = idx / NLOC;
    int loc = idx % NLOC;
    float mv[T_]; int mi[T_];
    #pragma unroll
    for (int t2 = 0; t2 < T_; t2++) {
        u64 k = gkey[(size_t)t2 * NLOC + loc];
        mv[t2] = __uint_as_float((unsigned)(k >> 32));
        mi[t2] = 255 - (int)(k & 0xFFFFFFFFu);
    }
    int nclamp = 0;
    #pragma unroll
    for (int t2 = 0; t2 < T_; t2++) nclamp += (mv[t2] > 0.f);
    int ft = T_ - nclamp; if (ft > T_ - 1) ft = T_ - 1;
    int wf = -1;
    #pragma unroll
    for (int t2 = 0; t2 < T_; t2++) if (t2 == ft) wf = mi[t2];
    if (!(mv[T_ - 1] > 0.f)) wf = -1;
    if (t == 0) winf[loc] = wf;

    float acc = 0.f;
    if (wf >= 0) {
        int y = loc / WP, x = loc % WP;
        const float* pb = P2 + (size_t)(t * F1) * P2S + (size_t)y * P2R + x;
        const float* wb = W2 + wf * 270;
        for (int c = 0; c < F1; c++) {                   // same c,ky,kx order as R2 conv
            #pragma unroll
            for (int ky = 0; ky < 3; ky++)
                #pragma unroll
                for (int kx = 0; kx < 3; kx++)
                    acc += wb[c * 9 + ky * 3 + kx] * pb[(size_t)c * P2S + ky * P2R + kx];
        }
    }
    acc = acc > THR2 ? acc : 0.f;                        // fire
    colv[t * NLOC + loc] = acc;
}

// ---------- per-loc k-WTA stats from exact columns ----------
__global__ void k_stat(const float* __restrict__ colv, int* __restrict__ nsA,
                       float* __restrict__ vfA, unsigned* __restrict__ vmax) {
    int loc = blockIdx.x * 256 + threadIdx.x;            // 6400 exact
    float col[T_];
    #pragma unroll
    for (int t = 0; t < T_; t++) col[t] = colv[t * NLOC + loc];
    int ns = 0;
    #pragma unroll
    for (int t = 0; t < T_; t++) ns += (col[t] > 0.f);
    int f2 = T_ - ns; if (f2 > T_ - 1) f2 = T_ - 1;
    float vf = 0.f;
    #pragma unroll
    for (int t = 0; t < T_; t++) if (t == f2) vf = col[t];
    nsA[loc] = ns; vfA[loc] = vf;
    atomicMax(vmax, __float_as_uint(vf));
}

// ---------- write-only expansion: spike2 + inhibited pot2 from compact columns ----------
__global__ void k_zero(float* __restrict__ outbuf, const int* __restrict__ winf,
                       const float* __restrict__ colv) {
    int idx = blockIdx.x * 256 + threadIdx.x;
    if (idx >= T_ * F2 * (NLOC / 4)) return;
    int l4 = idx % (NLOC / 4);
    int f  = (idx / (NLOC / 4)) % F2;
    int t  = idx / ((NLOC / 4) * F2);
    int loc = l4 * 4;
    int4   wf = *(const int4*)(winf + loc);
    float4 cv = *(const float4*)(colv + t * NLOC + loc);
    float4 po, sp;
    po.x = (wf.x == f) ? cv.x : 0.f;  sp.x = po.x > 0.f ? 1.f : 0.f;
    po.y = (wf.y == f) ? cv.y : 0.f;  sp.y = po.y > 0.f ? 1.f : 0.f;
    po.z = (wf.z == f) ? cv.z : 0.f;  sp.z = po.z > 0.f ? 1.f : 0.f;
    po.w = (wf.w == f) ? cv.w : 0.f;  sp.w = po.w > 0.f ? 1.f : 0.f;
    size_t off = ((size_t)t * F2 + f) * NLOC + loc;
    *(float4*)(outbuf + POT_OFF + off) = po;
    *(float4*)(outbuf + off) = sp;
}

// ---------- greedy k-WTA over compacted (one feature per loc) totals ----------
__global__ __launch_bounds__(256) void k_winners(const int* __restrict__ winf,
                                                 const int* __restrict__ nsA,
                                                 const float* __restrict__ vfA,
                                                 const unsigned* __restrict__ vmax,
                                                 float* __restrict__ wout) {
    __shared__ float tot[NLOC];
    __shared__ int   wfl[NLOC];
    __shared__ float rv[256];
    __shared__ int   rk[256];
    __shared__ float bvS; __shared__ int fiS, hiS, wiS;
    int tid = threadIdx.x;
    float v = __uint_as_float(vmax[0]) * (float)T_;
    for (int l = tid; l < NLOC; l += 256) {
        tot[l] = (float)nsA[l] * (vfA[l] + v);
        wfl[l] = winf[l];
    }
    __syncthreads();
    for (int it = 0; it < KWTA; it++) {
        float bv = 0.f; int bk = 0x7fffffff;
        #pragma unroll
        for (int i = 0; i < 25; i++) {
            int l = tid * 25 + i;
            float vv = tot[l];
            int k = wfl[l] * NLOC + l;
            if (vv > bv || (vv == bv && k < bk)) { bv = vv; bk = k; }
        }
        rv[tid] = bv; rk[tid] = bk;
        __syncthreads();
        for (int s = 128; s > 0; s >>= 1) {
            if (tid < s) {
                float v2 = rv[tid + s]; int k2 = rk[tid + s];
                if (v2 > rv[tid] || (v2 == rv[tid] && k2 < rk[tid])) { rv[tid] = v2; rk[tid] = k2; }
            }
            __syncthreads();
        }
        if (tid == 0) {
            float bvv = rv[0]; int bkk = rk[0];
            bool valid = bvv > 0.f;
            int fi = valid ? bkk / NLOC : -1;
            int lc = bkk % NLOC;
            int hi = valid ? lc / WP : -1;
            int wi = valid ? lc % WP : -1;
            wout[it * 3 + 0] = (float)fi;
            wout[it * 3 + 1] = (float)hi;
            wout[it * 3 + 2] = (float)wi;
            bvS = bvv; fiS = fi; hiS = hi; wiS = wi;
        }
        __syncthreads();
        if (bvS > 0.f) {
            #pragma unroll
            for (int i = 0; i < 25; i++) {
                int l = tid * 25 + i;
                int h = l / WP, w = l % WP;
                bool kill = (wfl[l] == fiS) ||
                            (h >= hiS - 1 && h <= hiS + 1 && w >= wiS - 1 && w <= wiS + 1);
                if (kill) tot[l] = 0.f;
            }
        }
        __syncthreads();
    }
}

extern "C" void kernel_launch(void* const* d_in, const int* in_sizes, int n_in,
                              void* d_out, int out_size, void* d_ws, size_t ws_size,
                              hipStream_t stream) {
    const float* data = (const float*)d_in[0];
    const float* W1   = (const float*)d_in[1];
    const float* W2   = (const float*)d_in[2];
    float* out = (float*)d_out;
    float* ws  = (float*)d_ws;

    // ws layout (floats): P2[3,175,200] Wf2[110,592] Wf1[10,752]
    //   winf[6400] ns[6400] vf[6400] colv[96,000] vmax[1] cnt[1] list[65,536] -> 13.9 MB
    float*    P2   = ws;
    u16*      Wf2  = (u16*)(ws + 3175200);
    u16*      Wf1  = (u16*)(ws + 3285792);
    int*      winf = (int*)(ws + 3296544);
    int*      nsA  = (int*)(ws + 3302944);
    float*    vfA  = ws + 3309344;
    float*    colv = ws + 3315744;
    unsigned* vmax = (unsigned*)(ws + 3411744);
    int*      cnt  = (int*)(ws + 3411745);
    int*      list = (int*)(ws + 3411746);

    // gkey (15 x 6400 u64 = 768 KB) lives in d_out's spike region (rewritten by k_zero)
    u64* gkey = (u64*)d_out;

    hipMemsetAsync(P2, 0, 3175200 * sizeof(float), stream);   // zero pool-map borders
    hipMemsetAsync(vmax, 0, 2 * sizeof(unsigned), stream);    // vmax + cnt

    k_wprep  <<<948, 256, 0, stream>>>(W2, W1, Wf2, Wf1);
    k_conv1m <<<dim3(100, T_), 256, 0, stream>>>(data, Wf1, P2, cnt, list);
    k_fix    <<<120, 256, 0, stream>>>(data, W1, P2, list, cnt);
    k_conv2m <<<dim3(100, T_), 256, 0, stream>>>(P2, Wf2, gkey);
    k_col    <<<375, 256, 0, stream>>>(gkey, P2, W2, winf, colv);
    k_stat   <<<25, 256, 0, stream>>>(colv, nsA, vfA, vmax);
    k_zero   <<<(T_ * F2 * (NLOC / 4) + 255) / 256, 256, 0, stream>>>(out, winf, colv);
    k_winners<<<1, 256, 0, stream>>>(winf, nsA, vfA, vmax, out + WIN_OFF);
}

// Round 6
// 403.836 us; speedup vs baseline: 1.1591x; 1.1591x over previous
//
#include <hip/hip_runtime.h>
#include <cstdint>

#define T_    15
#define C1    6
#define F1    30
#define THR1  15.0f
#define F2    250
#define THR2  10.0f
#define WP    80
#define NLOC  6400          // 80*80
#define KWTA  8
#define P2R   84
#define P2S   (84*84)       // padded pooled map (pad 1, rounded to 84 for float4 align)
#define POT_OFF 24000000    // d_out: [0,24M) spike2, [24M,48M) pot2, [48M,48M+24) winners
#define WIN_OFF 48000000
#define EPS1  2e-3f         // conv1 decision margin (>= 20x worst-case MFMA error ~1e-4)
#define FIXCAP 262144

typedef unsigned long long u64;
typedef unsigned short u16;
typedef short s16x8 __attribute__((ext_vector_type(8)));
typedef float f32x4 __attribute__((ext_vector_type(4)));

static __device__ __forceinline__ u16 f2bf(float x) {      // RNE fp32->bf16
    unsigned u = __float_as_uint(x);
    return (u16)((u + 0x7FFF + ((u >> 16) & 1)) >> 16);
}
static __device__ __forceinline__ float bf2f(u16 h) {
    return __uint_as_float(((unsigned)h) << 16);
}

// ---------- weight prep: bf16x3 splits in MFMA A-frag layout (W2 and W1) ----------
// Wf2 elem E = (((s*9+g)*16 + ft)*64 + lane)*8 + j ; A[m=lane&15][k=(lane>>4)*8+j]
//   f = ft*16 + (lane&15), c = k, g = ky*3+kx. f>=250 / c>=30 zero-padded.
// Wf1 elem E = (((sp*7+s)*2 + ft)*64 + lane)*8 + j
//   f = ft*16 + (lane&15) (<30), kp = s*4 + (lane>>4) = ky*5+kx (<25), c = j (<6).
// Tail: zero P2 border ring + vmax/cnt (replaces two hipMemsetAsync launches).
__global__ void k_wprep(const float* __restrict__ W2, const float* __restrict__ W1,
                        u16* __restrict__ Wf2, u16* __restrict__ Wf1,
                        float* __restrict__ P2, unsigned* __restrict__ vmax,
                        int* __restrict__ cnt) {
    int b = blockIdx.x;
    if (b < 864) {
        int E = b * 256 + threadIdx.x;                   // 221,184 exact
        int j    = E & 7;
        int lane = (E >> 3) & 63;
        int ft   = (E >> 9) & 15;
        int rest = E >> 13;                              // 0..26
        int s = rest / 9, g = rest % 9;
        int c = (lane >> 4) * 8 + j;
        int f = ft * 16 + (lane & 15);
        float w = (c < F1 && f < F2) ? W2[f * 270 + c * 9 + g] : 0.f;
        u16 h = f2bf(w);          float fh = bf2f(h);
        u16 m = f2bf(w - fh);     float fm = bf2f(m);
        u16 l = f2bf(w - fh - fm);
        Wf2[E] = (s == 0) ? h : (s == 1) ? m : l;
    } else {
        int E = (b - 864) * 256 + threadIdx.x;           // 21,504 exact
        int j    = E & 7;
        int lane = (E >> 3) & 63;
        int ft   = (E >> 9) & 1;
        int sf   = E >> 10;                              // 0..20
        int s = sf % 7, sp = sf / 7;
        int q = lane >> 4, m15 = lane & 15;
        int f  = ft * 16 + m15;
        int kp = s * 4 + q;
        int c  = j;
        float w = 0.f;
        if (f < F1 && kp < 25 && c < C1) {
            int ky = kp / 5, kx = kp % 5;
            w = W1[((f * C1 + c) * 5 + ky) * 5 + kx];
        }
        u16 h = f2bf(w);          float fh = bf2f(h);
        u16 m = f2bf(w - fh);     float fm = bf2f(m);
        u16 l = f2bf(w - fh - fm);
        Wf1[E] = (sp == 0) ? h : (sp == 1) ? m : l;
    }
    // P2 border ring: rows {0,81,82,83} x all cols + rows 1..80 x cols {0,81,82,83}
    int gtid = b * 256 + threadIdx.x;                    // 242,688 threads
    for (int idx = gtid; idx < 450 * 656; idx += 948 * 256) {
        int map = idx / 656, e = idx % 656;
        int row, col;
        if (e < 336) { int rs = e / 84; row = (rs == 0) ? 0 : 80 + rs; col = e % 84; }
        else { int e2 = e - 336; row = 1 + (e2 >> 2); int cs = e2 & 3; col = (cs == 0) ? 0 : 80 + cs; }
        P2[(size_t)map * P2S + (size_t)row * P2R + col] = 0.f;
    }
    if (gtid == 0) { *vmax = 0u; *cnt = 0; }
}

// ---------- conv1 via MFMA (bf16x3) + fire(15) + 2x2 maxpool + margin flags ----------
// grid (100, 15): block tile = 16 y x 16 x conv outputs, all 32 f (30 real).
// wave wv: conv rows y0+wv*4..+3 (nt), cols x0..x0+15 (n).
// Cells with any |pot-15|<EPS1 are appended to the fixup list (recomputed exactly).
__global__ __launch_bounds__(256) void k_conv1m(const float* __restrict__ data,
                                                const u16* __restrict__ Wf1,
                                                float* __restrict__ P2,
                                                int* __restrict__ cnt,
                                                int* __restrict__ list) {
    __shared__ u16 strip[3200];                          // [20 r][20 col][8 c] bf16
    __shared__ unsigned char pooled[2048];               // [8 py][8 px][32 f]
    int tid  = threadIdx.x;
    int lane = tid & 63;
    int wv   = __builtin_amdgcn_readfirstlane(tid >> 6);
    int t    = blockIdx.y;
    int xt = blockIdx.x % 10, yt = blockIdx.x / 10;
    int x0 = xt * 16, y0 = yt * 16;

    // stage input rows y0-2..y0+17, cols x0-2..x0+17 (bounds-checked virtual pad)
    for (int e = tid; e < 3200; e += 256) {              // e = (c*20 + r)*20 + cl
        int c = e / 400, r = (e / 20) % 20, cl = e % 20;
        int yy = y0 + r - 2, xx = x0 + cl - 2;
        float v = 0.f;
        if (c < C1 && yy >= 0 && yy < 160 && xx >= 0 && xx < 160)
            v = data[(size_t)(t * C1 + c) * 25600 + yy * 160 + xx];
        strip[(r * 20 + cl) * 8 + c] = f2bf(v);
    }
    __syncthreads();

    int q = lane >> 4, n = lane & 15;
    f32x4 acc[2][4];
    #pragma unroll
    for (int j = 0; j < 2; j++)
        #pragma unroll
        for (int nt = 0; nt < 4; nt++) acc[j][nt] = (f32x4)0.f;

    #pragma unroll
    for (int s = 0; s < 7; s++) {
        int kp = s * 4 + q;
        int ky = 0, kx = 0;
        if (kp < 25) { ky = kp / 5; kx = kp - ky * 5; }  // kp>=25: zero weights, read (0,0)
        s16x8 bf[4];
        #pragma unroll
        for (int nt = 0; nt < 4; nt++)
            bf[nt] = *(const s16x8*)&strip[((wv * 4 + nt + ky) * 20 + (n + kx)) * 8];
        #pragma unroll
        for (int sp = 0; sp < 3; sp++) {
            #pragma unroll
            for (int j = 0; j < 2; j++) {
                s16x8 af = *(const s16x8*)&Wf1[(size_t)(((sp * 7 + s) * 2 + j) * 64 + lane) * 8];
                #pragma unroll
                for (int nt = 0; nt < 4; nt++)
                    acc[j][nt] = __builtin_amdgcn_mfma_f32_16x16x32_bf16(af, bf[nt], acc[j][nt], 0, 0, 0);
            }
        }
    }

    // fire + flag; pool x via shfl_xor(1), y via nt pairs; even-n lanes own pooled px
    unsigned sb[4], nf[4];
    #pragma unroll
    for (int nt = 0; nt < 4; nt++) {
        unsigned s8 = 0, fl = 0;
        #pragma unroll
        for (int j = 0; j < 2; j++)
            #pragma unroll
            for (int r = 0; r < 4; r++) {
                float p = acc[j][nt][r];
                s8 |= (p > THR1 ? 1u : 0u) << (j * 4 + r);
                fl |= (fabsf(p - THR1) < EPS1 ? 1u : 0u);
            }
        sb[nt] = s8; nf[nt] = fl;
    }
    #pragma unroll
    for (int nt = 0; nt < 4; nt++) {
        sb[nt] |= (unsigned)__shfl_xor((int)sb[nt], 1, 64);
        nf[nt] |= (unsigned)__shfl_xor((int)nf[nt], 1, 64);
    }
    unsigned p0 = sb[0] | sb[1], p1 = sb[2] | sb[3];
    unsigned fw = (nf[0] | nf[1]) | ((nf[2] | nf[3]) << 1);
    fw |= (unsigned)__shfl_xor((int)fw, 16, 64);         // OR across q groups (dedupe)
    fw |= (unsigned)__shfl_xor((int)fw, 32, 64);
    if (!(n & 1)) {
        int px = n >> 1;
        #pragma unroll
        for (int j = 0; j < 2; j++)
            #pragma unroll
            for (int r = 0; r < 4; r++) {
                int f = j * 16 + q * 4 + r;
                pooled[((wv * 2 + 0) * 8 + px) * 32 + f] = (p0 >> (j * 4 + r)) & 1;
                pooled[((wv * 2 + 1) * 8 + px) * 32 + f] = (p1 >> (j * 4 + r)) & 1;
            }
        if (q == 0 && fw) {                              // one append per flagged cell
            int cb = t * NLOC + (yt * 8) * WP + (xt * 8 + px);
            if (fw & 1) { int id = atomicAdd(cnt, 1); if (id < FIXCAP) list[id] = cb + (wv * 2 + 0) * WP; }
            if (fw & 2) { int id = atomicAdd(cnt, 1); if (id < FIXCAP) list[id] = cb + (wv * 2 + 1) * WP; }
        }
    }
    __syncthreads();
    for (int i = tid; i < 1920; i += 256) {              // 30 f x 8 py x 8 px
        int f = i >> 6, pos = i & 63, py = pos >> 3, px = pos & 7;
        P2[(size_t)(t * F1 + f) * P2S + (size_t)(1 + yt * 8 + py) * P2R + (1 + xt * 8 + px)]
            = pooled[pos * 32 + f] ? 1.f : 0.f;
    }
}

// ---------- exact scalar recompute of flagged pooled cells (fp32 c,ky,kx order) ----------
__global__ void k_fix(const float* __restrict__ data, const float* __restrict__ W1,
                      float* __restrict__ P2, const int* __restrict__ list,
                      const int* __restrict__ cnt) {
    int m = *cnt; if (m > FIXCAP) m = FIXCAP;
    int nitems = m * F1;                                 // thread per (cell, f)
    for (int i = blockIdx.x * 256 + threadIdx.x; i < nitems; i += gridDim.x * 256) {
        int cell = list[i / F1], f = i % F1;
        int t = cell / NLOC, rem = cell % NLOC, py = rem / WP, px = rem % WP;
        bool s = false;
        #pragma unroll
        for (int dy = 0; dy < 2; dy++)
            #pragma unroll
            for (int dx = 0; dx < 2; dx++) {
                int y = 2 * py + dy, x = 2 * px + dx;    // conv output coords
                float acc = 0.f;
                for (int c = 0; c < C1; c++)
                    #pragma unroll
                    for (int ky = 0; ky < 5; ky++)
                        #pragma unroll
                        for (int kx = 0; kx < 5; kx++) {
                            int yy = y + ky - 2, xx = x + kx - 2;
                            float v = (yy >= 0 && yy < 160 && xx >= 0 && xx < 160)
                                ? data[(size_t)(t * C1 + c) * 25600 + yy * 160 + xx] : 0.f;
                            acc += W1[((f * C1 + c) * 5 + ky) * 5 + kx] * v;
                        }
                s |= acc > THR1;
            }
        P2[(size_t)(t * F1 + f) * P2S + (size_t)(1 + py) * P2R + (1 + px)] = s ? 1.f : 0.f;
    }
}

// ---------- conv2 via MFMA (bf16x3, two-bank order) + fire + per-(t,loc) argmax ----------
// grid (100, 15): block tile = 256 f x (4 rows x 16 cols). wave = 64 f x 64 locs.
__global__ __launch_bounds__(256) void k_conv2m(const float* __restrict__ P2,
                                                const u16* __restrict__ Wf,
                                                u64* __restrict__ gkey) {
    __shared__ u16 rawT[3456];                           // [6 r][4 q][18 col][8] bf16
    __shared__ u64 skey[256];                            // [wv][nt][n]
    int tid  = threadIdx.x;
    int lane = tid & 63;
    int wv   = __builtin_amdgcn_readfirstlane(tid >> 6);
    int t    = blockIdx.y;
    int xt = blockIdx.x % 5, yt = blockIdx.x / 5;
    int y0 = yt * 4, x0 = xt * 16;

    // stage strip rows y0..y0+5, cols x0..x0+17, 30ch (c-quad-major: 16B lane stride)
    for (int e = tid; e < 3456; e += 256) {              // e = (c*6 + r)*18 + col
        int c = e / 108, r = (e / 18) % 6, col = e % 18;
        float v = (c < F1)
            ? P2[(size_t)(t * F1 + c) * P2S + (size_t)(y0 + r) * P2R + (x0 + col)] : 0.f;
        rawT[((r * 4 + (c >> 3)) * 18 + col) * 8 + (c & 7)] = f2bf(v);
    }
    __syncthreads();

    int q = lane >> 4, n = lane & 15;
    f32x4 accA[4][4], accB[4][4];                        // [j(ftile)][nt]: hi | mid+lo
    #pragma unroll
    for (int j = 0; j < 4; j++)
        #pragma unroll
        for (int nt = 0; nt < 4; nt++) { accA[j][nt] = (f32x4)0.f; accB[j][nt] = (f32x4)0.f; }

    #pragma unroll
    for (int ky = 0; ky < 3; ky++) {
        #pragma unroll
        for (int kx = 0; kx < 3; kx++) {
            int g = ky * 3 + kx;
            s16x8 bf[4];
            #pragma unroll
            for (int nt = 0; nt < 4; nt++)
                bf[nt] = *(const s16x8*)&rawT[(((nt + ky) * 4 + q) * 18 + (n + kx)) * 8];
            #pragma unroll
            for (int s = 0; s < 3; s++) {
                #pragma unroll
                for (int j = 0; j < 4; j++) {
                    s16x8 af = *(const s16x8*)&Wf[(size_t)((((s * 9 + g) * 16) + (wv * 4 + j)) * 64 + lane) * 8];
                    if (s == 0) {
                        #pragma unroll
                        for (int nt = 0; nt < 4; nt++)
                            accA[j][nt] = __builtin_amdgcn_mfma_f32_16x16x32_bf16(af, bf[nt], accA[j][nt], 0, 0, 0);
                    } else {
                        #pragma unroll
                        for (int nt = 0; nt < 4; nt++)
                            accB[j][nt] = __builtin_amdgcn_mfma_f32_16x16x32_bf16(af, bf[nt], accB[j][nt], 0, 0, 0);
                    }
                }
            }
        }
    }

    // epilogue: fire + key(val, 255-f), reduce rows/lane, then q-lanes, then waves
    #pragma unroll
    for (int nt = 0; nt < 4; nt++) {
        u64 best = 0;
        #pragma unroll
        for (int j = 0; j < 4; j++) {
            #pragma unroll
            for (int r = 0; r < 4; r++) {
                float pot = accA[j][nt][r] + accB[j][nt][r];
                float rr  = pot > THR2 ? pot : 0.f;
                int f = (wv * 4 + j) * 16 + q * 4 + r;
                u64 key = ((u64)__float_as_uint(rr) << 32) | (u64)(unsigned)(255 - f);
                best = best > key ? best : key;
            }
        }
        u64 o = __shfl_xor(best, 16, 64); best = best > o ? best : o;
        o     = __shfl_xor(best, 32, 64); best = best > o ? best : o;
        if (q == 0) skey[(wv * 4 + nt) * 16 + n] = best;
    }
    __syncthreads();
    if (tid < 64) {
        int nt2 = tid >> 4, n2 = tid & 15;
        u64 bk = skey[nt2 * 16 + n2];
        #pragma unroll
        for (int w = 1; w < 4; w++) {
            u64 k = skey[(w * 4 + nt2) * 16 + n2];
            bk = bk > k ? bk : k;
        }
        gkey[(size_t)t * NLOC + (size_t)(y0 + nt2) * WP + (x0 + n2)] = bk;
    }
}

// ---------- per-(t,loc): winner logic + exact fp32 recompute of winner column ----------
__global__ void k_col(const u64* __restrict__ gkey, const float* __restrict__ P2,
                      const float* __restrict__ W2, int* __restrict__ winf,
                      float* __restrict__ colv) {
    int idx = blockIdx.x * 256 + threadIdx.x;            // 96,000 exact
    int t   = idx / NLOC;
    int loc = idx % NLOC;
    float mv[T_]; int mi[T_];
    #pragma unroll
    for (int t2 = 0; t2 < T_; t2++) {
        u64 k = gkey[(size_t)t2 * NLOC + loc];
        mv[t2] = __uint_as_float((unsigned)(k >> 32));
        mi[t2] = 255 - (int)(k & 0xFFFFFFFFu);
    }
    int nclamp = 0;
    #pragma unroll
    for (int t2 = 0; t2 < T_; t2++) nclamp += (mv[t2] > 0.f);
    int ft = T_ - nclamp; if (ft > T_ - 1) ft = T_ - 1;
    int wf = -1;
    #pragma unroll
    for (int t2 = 0; t2 < T_; t2++) if (t2 == ft) wf = mi[t2];
    if (!(mv[T_ - 1] > 0.f)) wf = -1;
    if (t == 0) winf[loc] = wf;

    float acc = 0.f;
    if (wf >= 0) {
        int y = loc / WP, x = loc % WP;
        const float* pb = P2 + (size_t)(t * F1) * P2S + (size_t)y * P2R + x;
        const float* wb = W2 + wf * 270;
        for (int c = 0; c < F1; c++) {                   // same c,ky,kx order as R2 conv
            #pragma unroll
            for (int ky = 0; ky < 3; ky++)
                #pragma unroll
                for (int kx = 0; kx < 3; kx++)
                    acc += wb[c * 9 + ky * 3 + kx] * pb[(size_t)c * P2S + ky * P2R + kx];
        }
    }
    acc = acc > THR2 ? acc : 0.f;                        // fire
    colv[t * NLOC + loc] = acc;
}

// ---------- per-loc k-WTA stats from exact columns ----------
__global__ void k_stat(const float* __restrict__ colv, int* __restrict__ nsA,
                       float* __restrict__ vfA, unsigned* __restrict__ vmax) {
    int loc = blockIdx.x * 256 + threadIdx.x;            // 6400 exact
    float col[T_];
    #pragma unroll
    for (int t = 0; t < T_; t++) col[t] = colv[t * NLOC + loc];
    int ns = 0;
    #pragma unroll
    for (int t = 0; t < T_; t++) ns += (col[t] > 0.f);
    int f2 = T_ - ns; if (f2 > T_ - 1) f2 = T_ - 1;
    float vf = 0.f;
    #pragma unroll
    for (int t = 0; t < T_; t++) if (t == f2) vf = col[t];
    nsA[loc] = ns; vfA[loc] = vf;
    atomicMax(vmax, __float_as_uint(vf));
}

// ---------- write-only expansion: spike2 + inhibited pot2 from compact columns ----------
__global__ void k_zero(float* __restrict__ outbuf, const int* __restrict__ winf,
                       const float* __restrict__ colv) {
    int idx = blockIdx.x * 256 + threadIdx.x;
    if (idx >= T_ * F2 * (NLOC / 4)) return;
    int l4 = idx % (NLOC / 4);
    int f  = (idx / (NLOC / 4)) % F2;
    int t  = idx / ((NLOC / 4) * F2);
    int loc = l4 * 4;
    int4   wf = *(const int4*)(winf + loc);
    float4 cv = *(const float4*)(colv + t * NLOC + loc);
    float4 po, sp;
    po.x = (wf.x == f) ? cv.x : 0.f;  sp.x = po.x > 0.f ? 1.f : 0.f;
    po.y = (wf.y == f) ? cv.y : 0.f;  sp.y = po.y > 0.f ? 1.f : 0.f;
    po.z = (wf.z == f) ? cv.z : 0.f;  sp.z = po.z > 0.f ? 1.f : 0.f;
    po.w = (wf.w == f) ? cv.w : 0.f;  sp.w = po.w > 0.f ? 1.f : 0.f;
    size_t off = ((size_t)t * F2 + f) * NLOC + loc;
    *(float4*)(outbuf + POT_OFF + off) = po;
    *(float4*)(outbuf + off) = sp;
}

// ---------- greedy k-WTA; wave-shuffle reduction (3 syncs/iter) ----------
__global__ __launch_bounds__(256) void k_winners(const int* __restrict__ winf,
                                                 const int* __restrict__ nsA,
                                                 const float* __restrict__ vfA,
                                                 const unsigned* __restrict__ vmax,
                                                 float* __restrict__ wout) {
    __shared__ float tot[NLOC];
    __shared__ int   wfl[NLOC];
    __shared__ u64   rw[4];
    __shared__ float bvS; __shared__ int fiS, hiS, wiS;
    int tid = threadIdx.x;
    int lane = tid & 63, wv = tid >> 6;
    float v = __uint_as_float(vmax[0]) * (float)T_;
    for (int l = tid; l < NLOC; l += 256) {
        tot[l] = (float)nsA[l] * (vfA[l] + v);           // ns==0 -> 0; same fp ops as ref path
        wfl[l] = winf[l];
    }
    __syncthreads();
    for (int it = 0; it < KWTA; it++) {
        float bv = 0.f; int bk = 0x7fffffff;
        #pragma unroll
        for (int i = 0; i < 25; i++) {
            int l = tid * 25 + i;
            float vv = tot[l];
            int k = wfl[l] * NLOC + l;                   // flattened (f,h,w) index
            if (vv > bv || (vv == bv && k < bk)) { bv = vv; bk = k; }
        }
        // packed key: value desc, then smaller flat index wins
        u64 key = ((u64)__float_as_uint(bv) << 32) | (u64)(unsigned)(0x7fffffff - bk);
        #pragma unroll
        for (int s = 1; s < 64; s <<= 1) {
            u64 o = __shfl_xor(key, s, 64);
            key = key > o ? key : o;
        }
        if (lane == 0) rw[wv] = key;
        __syncthreads();
        if (tid == 0) {
            u64 k0 = rw[0], k1 = rw[1], k2 = rw[2], k3 = rw[3];
            u64 ka = k0 > k1 ? k0 : k1, kb = k2 > k3 ? k2 : k3;
            u64 kk = ka > kb ? ka : kb;
            float bvv = __uint_as_float((unsigned)(kk >> 32));
            int bkk = 0x7fffffff - (int)(kk & 0xFFFFFFFFu);
            bool valid = bvv > 0.f;
            int fi = valid ? bkk / NLOC : -1;
            int lc = bkk % NLOC;
            int hi = valid ? lc / WP : -1;
            int wi = valid ? lc % WP : -1;
            wout[it * 3 + 0] = (float)fi;
            wout[it * 3 + 1] = (float)hi;
            wout[it * 3 + 2] = (float)wi;
            bvS = bvv; fiS = fi; hiS = hi; wiS = wi;
        }
        __syncthreads();
        if (bvS > 0.f) {
            #pragma unroll
            for (int i = 0; i < 25; i++) {
                int l = tid * 25 + i;
                int h = l / WP, w = l % WP;
                bool kill = (wfl[l] == fiS) ||
                            (h >= hiS - 1 && h <= hiS + 1 && w >= wiS - 1 && w <= wiS + 1);
                if (kill) tot[l] = 0.f;
            }
        }
        __syncthreads();
    }
}

extern "C" void kernel_launch(void* const* d_in, const int* in_sizes, int n_in,
                              void* d_out, int out_size, void* d_ws, size_t ws_size,
                              hipStream_t stream) {
    const float* data = (const float*)d_in[0];
    const float* W1   = (const float*)d_in[1];
    const float* W2   = (const float*)d_in[2];
    float* out = (float*)d_out;
    float* ws  = (float*)d_ws;

    // ws layout (floats): P2[3,175,200] Wf2[110,592] Wf1[10,752]
    //   winf[6400] ns[6400] vf[6400] colv[96,000] vmax[1] cnt[1] list[262,144] -> 14.7 MB
    float*    P2   = ws;
    u16*      Wf2  = (u16*)(ws + 3175200);
    u16*      Wf1  = (u16*)(ws + 3285792);
    int*      winf = (int*)(ws + 3296544);
    int*      nsA  = (int*)(ws + 3302944);
    float*    vfA  = ws + 3309344;
    float*    colv = ws + 3315744;
    unsigned* vmax = (unsigned*)(ws + 3411744);
    int*      cnt  = (int*)(ws + 3411745);
    int*      list = (int*)(ws + 3411746);

    // gkey (15 x 6400 u64 = 768 KB) lives in d_out's spike region (rewritten by k_zero)
    u64* gkey = (u64*)d_out;

    k_wprep  <<<948, 256, 0, stream>>>(W2, W1, Wf2, Wf1, P2, vmax, cnt);
    k_conv1m <<<dim3(100, T_), 256, 0, stream>>>(data, Wf1, P2, cnt, list);
    k_fix    <<<2048, 256, 0, stream>>>(data, W1, P2, list, cnt);
    k_conv2m <<<dim3(100, T_), 256, 0, stream>>>(P2, Wf2, gkey);
    k_col    <<<375, 256, 0, stream>>>(gkey, P2, W2, winf, colv);
    k_stat   <<<25, 256, 0, stream>>>(colv, nsA, vfA, vmax);
    k_zero   <<<(T_ * F2 * (NLOC / 4) + 255) / 256, 256, 0, stream>>>(out, winf, colv);
    k_winners<<<1, 256, 0, stream>>>(winf, nsA, vfA, vmax, out + WIN_OFF);
}

// Round 7
// 392.573 us; speedup vs baseline: 1.1923x; 1.0287x over previous
//
#include <hip/hip_runtime.h>
#include <cstdint>

#define T_    15
#define C1    6
#define F1    30
#define THR1  15.0f
#define F2    250
#define THR2  10.0f
#define WP    80
#define NLOC  6400          // 80*80
#define KWTA  8
#define P2R   84
#define P2S   (84*84)       // padded pooled map (pad 1, rounded to 84 for float4 align)
#define POT_OFF 24000000    // d_out: [0,24M) spike2, [24M,48M) pot2, [48M,48M+24) winners
#define WIN_OFF 48000000
#define EPS1  1e-3f         // conv1 decision margin (>=3x pessimistic reorder bound 3e-4)
#define FIXCAP 262144

typedef unsigned long long u64;
typedef unsigned short u16;
typedef short s16x8 __attribute__((ext_vector_type(8)));
typedef float f32x4 __attribute__((ext_vector_type(4)));

static __device__ __forceinline__ u16 f2bf(float x) {      // RNE fp32->bf16
    unsigned u = __float_as_uint(x);
    return (u16)((u + 0x7FFF + ((u >> 16) & 1)) >> 16);
}
static __device__ __forceinline__ float bf2f(u16 h) {
    return __uint_as_float(((unsigned)h) << 16);
}

// ---------- weight prep: bf16x3 splits in MFMA A-frag layout (W2 and W1) ----------
// Wf2 elem E = (((s*9+g)*16 + ft)*64 + lane)*8 + j ; A[m=lane&15][k=(lane>>4)*8+j]
//   f = ft*16 + (lane&15), c = k, g = ky*3+kx. f>=250 / c>=30 zero-padded.
// Wf1 elem E = (((sp*7+s)*2 + ft)*64 + lane)*8 + j
//   f = ft*16 + (lane&15) (<30), kp = s*4 + (lane>>4) = ky*5+kx (<25), c = j (<6).
// Tail: zero P2 border ring + vmax/cnt (replaces two hipMemsetAsync launches).
__global__ void k_wprep(const float* __restrict__ W2, const float* __restrict__ W1,
                        u16* __restrict__ Wf2, u16* __restrict__ Wf1,
                        float* __restrict__ P2, unsigned* __restrict__ vmax,
                        int* __restrict__ cnt) {
    int b = blockIdx.x;
    if (b < 864) {
        int E = b * 256 + threadIdx.x;                   // 221,184 exact
        int j    = E & 7;
        int lane = (E >> 3) & 63;
        int ft   = (E >> 9) & 15;
        int rest = E >> 13;                              // 0..26
        int s = rest / 9, g = rest % 9;
        int c = (lane >> 4) * 8 + j;
        int f = ft * 16 + (lane & 15);
        float w = (c < F1 && f < F2) ? W2[f * 270 + c * 9 + g] : 0.f;
        u16 h = f2bf(w);          float fh = bf2f(h);
        u16 m = f2bf(w - fh);     float fm = bf2f(m);
        u16 l = f2bf(w - fh - fm);
        Wf2[E] = (s == 0) ? h : (s == 1) ? m : l;
    } else {
        int E = (b - 864) * 256 + threadIdx.x;           // 21,504 exact
        int j    = E & 7;
        int lane = (E >> 3) & 63;
        int ft   = (E >> 9) & 1;
        int sf   = E >> 10;                              // 0..20
        int s = sf % 7, sp = sf / 7;
        int q = lane >> 4, m15 = lane & 15;
        int f  = ft * 16 + m15;
        int kp = s * 4 + q;
        int c  = j;
        float w = 0.f;
        if (f < F1 && kp < 25 && c < C1) {
            int ky = kp / 5, kx = kp % 5;
            w = W1[((f * C1 + c) * 5 + ky) * 5 + kx];
        }
        u16 h = f2bf(w);          float fh = bf2f(h);
        u16 m = f2bf(w - fh);     float fm = bf2f(m);
        u16 l = f2bf(w - fh - fm);
        Wf1[E] = (sp == 0) ? h : (sp == 1) ? m : l;
    }
    // P2 border ring: rows {0,81,82,83} x all cols + rows 1..80 x cols {0,81,82,83}
    int gtid = b * 256 + threadIdx.x;                    // 242,688 threads
    for (int idx = gtid; idx < 450 * 656; idx += 948 * 256) {
        int map = idx / 656, e = idx % 656;
        int row, col;
        if (e < 336) { int rs = e / 84; row = (rs == 0) ? 0 : 80 + rs; col = e % 84; }
        else { int e2 = e - 336; row = 1 + (e2 >> 2); int cs = e2 & 3; col = (cs == 0) ? 0 : 80 + cs; }
        P2[(size_t)map * P2S + (size_t)row * P2R + col] = 0.f;
    }
    if (gtid == 0) { *vmax = 0u; *cnt = 0; }
}

// ---------- conv1 via MFMA (bf16x3) + fire(15) + 2x2 maxpool + margin flags ----------
// grid (100, 15): block tile = 16 y x 16 x conv outputs, all 32 f (30 real).
// wave wv: conv rows y0+wv*4..+3 (nt), cols x0..x0+15 (n).
// Cells with any |pot-15|<EPS1 are appended to the fixup list (recomputed exactly).
__global__ __launch_bounds__(256) void k_conv1m(const float* __restrict__ data,
                                                const u16* __restrict__ Wf1,
                                                float* __restrict__ P2,
                                                int* __restrict__ cnt,
                                                int* __restrict__ list) {
    __shared__ u16 strip[3200];                          // [20 r][20 col][8 c] bf16
    __shared__ unsigned char pooled[2048];               // [8 py][8 px][32 f]
    int tid  = threadIdx.x;
    int lane = tid & 63;
    int wv   = __builtin_amdgcn_readfirstlane(tid >> 6);
    int t    = blockIdx.y;
    int xt = blockIdx.x % 10, yt = blockIdx.x / 10;
    int x0 = xt * 16, y0 = yt * 16;

    // stage input rows y0-2..y0+17, cols x0-2..x0+17 (bounds-checked virtual pad)
    for (int e = tid; e < 3200; e += 256) {              // e = (c*20 + r)*20 + cl
        int c = e / 400, r = (e / 20) % 20, cl = e % 20;
        int yy = y0 + r - 2, xx = x0 + cl - 2;
        float v = 0.f;
        if (c < C1 && yy >= 0 && yy < 160 && xx >= 0 && xx < 160)
            v = data[(size_t)(t * C1 + c) * 25600 + yy * 160 + xx];
        strip[(r * 20 + cl) * 8 + c] = f2bf(v);
    }
    __syncthreads();

    int q = lane >> 4, n = lane & 15;
    f32x4 acc[2][4];
    #pragma unroll
    for (int j = 0; j < 2; j++)
        #pragma unroll
        for (int nt = 0; nt < 4; nt++) acc[j][nt] = (f32x4)0.f;

    #pragma unroll
    for (int s = 0; s < 7; s++) {
        int kp = s * 4 + q;
        int ky = 0, kx = 0;
        if (kp < 25) { ky = kp / 5; kx = kp - ky * 5; }  // kp>=25: zero weights, read (0,0)
        s16x8 bf[4];
        #pragma unroll
        for (int nt = 0; nt < 4; nt++)
            bf[nt] = *(const s16x8*)&strip[((wv * 4 + nt + ky) * 20 + (n + kx)) * 8];
        #pragma unroll
        for (int sp = 0; sp < 3; sp++) {
            #pragma unroll
            for (int j = 0; j < 2; j++) {
                s16x8 af = *(const s16x8*)&Wf1[(size_t)(((sp * 7 + s) * 2 + j) * 64 + lane) * 8];
                #pragma unroll
                for (int nt = 0; nt < 4; nt++)
                    acc[j][nt] = __builtin_amdgcn_mfma_f32_16x16x32_bf16(af, bf[nt], acc[j][nt], 0, 0, 0);
            }
        }
    }

    // fire + flag; pool x via shfl_xor(1), y via nt pairs; even-n lanes own pooled px
    unsigned sb[4], nf[4];
    #pragma unroll
    for (int nt = 0; nt < 4; nt++) {
        unsigned s8 = 0, fl = 0;
        #pragma unroll
        for (int j = 0; j < 2; j++)
            #pragma unroll
            for (int r = 0; r < 4; r++) {
                float p = acc[j][nt][r];
                s8 |= (p > THR1 ? 1u : 0u) << (j * 4 + r);
                fl |= (fabsf(p - THR1) < EPS1 ? 1u : 0u);
            }
        sb[nt] = s8; nf[nt] = fl;
    }
    #pragma unroll
    for (int nt = 0; nt < 4; nt++) {
        sb[nt] |= (unsigned)__shfl_xor((int)sb[nt], 1, 64);
        nf[nt] |= (unsigned)__shfl_xor((int)nf[nt], 1, 64);
    }
    unsigned p0 = sb[0] | sb[1], p1 = sb[2] | sb[3];
    unsigned fw = (nf[0] | nf[1]) | ((nf[2] | nf[3]) << 1);
    fw |= (unsigned)__shfl_xor((int)fw, 16, 64);         // OR across q groups (dedupe)
    fw |= (unsigned)__shfl_xor((int)fw, 32, 64);
    if (!(n & 1)) {
        int px = n >> 1;
        #pragma unroll
        for (int j = 0; j < 2; j++)
            #pragma unroll
            for (int r = 0; r < 4; r++) {
                int f = j * 16 + q * 4 + r;
                pooled[((wv * 2 + 0) * 8 + px) * 32 + f] = (p0 >> (j * 4 + r)) & 1;
                pooled[((wv * 2 + 1) * 8 + px) * 32 + f] = (p1 >> (j * 4 + r)) & 1;
            }
        if (q == 0 && fw) {                              // one append per flagged cell
            int cb = t * NLOC + (yt * 8) * WP + (xt * 8 + px);
            if (fw & 1) { int id = atomicAdd(cnt, 1); if (id < FIXCAP) list[id] = cb + (wv * 2 + 0) * WP; }
            if (fw & 2) { int id = atomicAdd(cnt, 1); if (id < FIXCAP) list[id] = cb + (wv * 2 + 1) * WP; }
        }
    }
    __syncthreads();
    for (int i = tid; i < 1920; i += 256) {              // 30 f x 8 py x 8 px
        int f = i >> 6, pos = i & 63, py = pos >> 3, px = pos & 7;
        P2[(size_t)(t * F1 + f) * P2S + (size_t)(1 + yt * 8 + py) * P2R + (1 + xt * 8 + px)]
            = pooled[pos * 32 + f] ? 1.f : 0.f;
    }
}

// ---------- exact scalar recompute of flagged pooled cells (fp32 c,ky,kx order) ----------
__global__ void k_fix(const float* __restrict__ data, const float* __restrict__ W1,
                      float* __restrict__ P2, const int* __restrict__ list,
                      const int* __restrict__ cnt) {
    int m = *cnt; if (m > FIXCAP) m = FIXCAP;
    int nitems = m * F1;                                 // thread per (cell, f)
    for (int i = blockIdx.x * 256 + threadIdx.x; i < nitems; i += gridDim.x * 256) {
        int cell = list[i / F1], f = i % F1;
        int t = cell / NLOC, rem = cell % NLOC, py = rem / WP, px = rem % WP;
        bool s = false;
        #pragma unroll
        for (int dy = 0; dy < 2; dy++)
            #pragma unroll
            for (int dx = 0; dx < 2; dx++) {
                int y = 2 * py + dy, x = 2 * px + dx;    // conv output coords
                float acc = 0.f;
                for (int c = 0; c < C1; c++)
                    #pragma unroll
                    for (int ky = 0; ky < 5; ky++)
                        #pragma unroll
                        for (int kx = 0; kx < 5; kx++) {
                            int yy = y + ky - 2, xx = x + kx - 2;
                            float v = (yy >= 0 && yy < 160 && xx >= 0 && xx < 160)
                                ? data[(size_t)(t * C1 + c) * 25600 + yy * 160 + xx] : 0.f;
                            acc += W1[((f * C1 + c) * 5 + ky) * 5 + kx] * v;
                        }
                s |= acc > THR1;
            }
        P2[(size_t)(t * F1 + f) * P2S + (size_t)(1 + py) * P2R + (1 + px)] = s ? 1.f : 0.f;
    }
}

// ---------- conv2 via MFMA (bf16x3, two-bank order) + fire + per-(t,loc) argmax ----------
// grid (100, 15): block tile = 256 f x (4 rows x 16 cols). wave = 64 f x 64 locs.
__global__ __launch_bounds__(256) void k_conv2m(const float* __restrict__ P2,
                                                const u16* __restrict__ Wf,
                                                u64* __restrict__ gkey) {
    __shared__ u16 rawT[3456];                           // [6 r][4 q][18 col][8] bf16
    __shared__ u64 skey[256];                            // [wv][nt][n]
    int tid  = threadIdx.x;
    int lane = tid & 63;
    int wv   = __builtin_amdgcn_readfirstlane(tid >> 6);
    int t    = blockIdx.y;
    int xt = blockIdx.x % 5, yt = blockIdx.x / 5;
    int y0 = yt * 4, x0 = xt * 16;

    // stage strip rows y0..y0+5, cols x0..x0+17, 30ch, vectorized (no bounds: P2 padded)
    // e<900: (c,r) pair = e/5, seg = e%5 (4x float4 + 1x float2); e>=900: zero c=30,31
    for (int e = tid; e < 1116; e += 256) {
        if (e < 900) {
            int pair = e / 5, seg = e - pair * 5;
            int c = pair / 6, r = pair - c * 6;
            const float* src = P2 + (size_t)(t * F1 + c) * P2S + (size_t)(y0 + r) * P2R + x0;
            int base = ((r * 4 + (c >> 3)) * 18) * 8 + (c & 7);
            if (seg < 4) {
                float4 v = *(const float4*)(src + 4 * seg);
                rawT[base + (4 * seg + 0) * 8] = f2bf(v.x);
                rawT[base + (4 * seg + 1) * 8] = f2bf(v.y);
                rawT[base + (4 * seg + 2) * 8] = f2bf(v.z);
                rawT[base + (4 * seg + 3) * 8] = f2bf(v.w);
            } else {
                float2 v = *(const float2*)(src + 16);
                rawT[base + 16 * 8] = f2bf(v.x);
                rawT[base + 17 * 8] = f2bf(v.y);
            }
        } else {
            int e2 = e - 900;                            // 216: c in {30,31} x 6r x 18col
            int c = 30 + e2 / 108, rem = e2 % 108, r = rem / 18, col = rem % 18;
            rawT[((r * 4 + (c >> 3)) * 18 + col) * 8 + (c & 7)] = 0;
        }
    }
    __syncthreads();

    int q = lane >> 4, n = lane & 15;
    f32x4 accA[4][4], accB[4][4];                        // [j(ftile)][nt]: hi | mid+lo
    #pragma unroll
    for (int j = 0; j < 4; j++)
        #pragma unroll
        for (int nt = 0; nt < 4; nt++) { accA[j][nt] = (f32x4)0.f; accB[j][nt] = (f32x4)0.f; }

    #pragma unroll
    for (int ky = 0; ky < 3; ky++) {
        #pragma unroll
        for (int kx = 0; kx < 3; kx++) {
            int g = ky * 3 + kx;
            s16x8 bf[4];
            #pragma unroll
            for (int nt = 0; nt < 4; nt++)
                bf[nt] = *(const s16x8*)&rawT[(((nt + ky) * 4 + q) * 18 + (n + kx)) * 8];
            #pragma unroll
            for (int s = 0; s < 3; s++) {
                #pragma unroll
                for (int j = 0; j < 4; j++) {
                    s16x8 af = *(const s16x8*)&Wf[(size_t)((((s * 9 + g) * 16) + (wv * 4 + j)) * 64 + lane) * 8];
                    if (s == 0) {
                        #pragma unroll
                        for (int nt = 0; nt < 4; nt++)
                            accA[j][nt] = __builtin_amdgcn_mfma_f32_16x16x32_bf16(af, bf[nt], accA[j][nt], 0, 0, 0);
                    } else {
                        #pragma unroll
                        for (int nt = 0; nt < 4; nt++)
                            accB[j][nt] = __builtin_amdgcn_mfma_f32_16x16x32_bf16(af, bf[nt], accB[j][nt], 0, 0, 0);
                    }
                }
            }
        }
    }

    // epilogue: fire + key(val, 255-f), reduce rows/lane, then q-lanes, then waves
    #pragma unroll
    for (int nt = 0; nt < 4; nt++) {
        u64 best = 0;
        #pragma unroll
        for (int j = 0; j < 4; j++) {
            #pragma unroll
            for (int r = 0; r < 4; r++) {
                float pot = accA[j][nt][r] + accB[j][nt][r];
                float rr  = pot > THR2 ? pot : 0.f;
                int f = (wv * 4 + j) * 16 + q * 4 + r;
                u64 key = ((u64)__float_as_uint(rr) << 32) | (u64)(unsigned)(255 - f);
                best = best > key ? best : key;
            }
        }
        u64 o = __shfl_xor(best, 16, 64); best = best > o ? best : o;
        o     = __shfl_xor(best, 32, 64); best = best > o ? best : o;
        if (q == 0) skey[(wv * 4 + nt) * 16 + n] = best;
    }
    __syncthreads();
    if (tid < 64) {
        int nt2 = tid >> 4, n2 = tid & 15;
        u64 bk = skey[nt2 * 16 + n2];
        #pragma unroll
        for (int w = 1; w < 4; w++) {
            u64 k = skey[(w * 4 + nt2) * 16 + n2];
            bk = bk > k ? bk : k;
        }
        gkey[(size_t)t * NLOC + (size_t)(y0 + nt2) * WP + (x0 + n2)] = bk;
    }
}

// ---------- per-(t,loc): winner logic + exact fp32 recompute of winner column ----------
// wb loads vectorized float2 (wf*270 even -> 8B aligned); FMA order = flat c,ky,kx,
// bit-identical to R6's scalar loop.
__global__ __launch_bounds__(128) void k_col(const u64* __restrict__ gkey,
                                             const float* __restrict__ P2,
                                             const float* __restrict__ W2,
                                             int* __restrict__ winf,
                                             float* __restrict__ colv) {
    int idx = blockIdx.x * 128 + threadIdx.x;            // 96,000 exact (750 blocks)
    int t   = idx / NLOC;
    int loc = idx % NLOC;
    float mv[T_]; int mi[T_];
    #pragma unroll
    for (int t2 = 0; t2 < T_; t2++) {
        u64 k = gkey[(size_t)t2 * NLOC + loc];
        mv[t2] = __uint_as_float((unsigned)(k >> 32));
        mi[t2] = 255 - (int)(k & 0xFFFFFFFFu);
    }
    int nclamp = 0;
    #pragma unroll
    for (int t2 = 0; t2 < T_; t2++) nclamp += (mv[t2] > 0.f);
    int ft = T_ - nclamp; if (ft > T_ - 1) ft = T_ - 1;
    int wf = -1;
    #pragma unroll
    for (int t2 = 0; t2 < T_; t2++) if (t2 == ft) wf = mi[t2];
    if (!(mv[T_ - 1] > 0.f)) wf = -1;
    if (t == 0) winf[loc] = wf;

    float acc = 0.f;
    if (wf >= 0) {
        int y = loc / WP, x = loc % WP;
        const float*  pb  = P2 + (size_t)(t * F1) * P2S + (size_t)y * P2R + x;
        const float2* wb2 = (const float2*)(W2 + wf * 270);
        #pragma unroll
        for (int i2 = 0; i2 < 135; i2++) {               // i = 2*i2 (+1): flat c,ky,kx
            float2 w2 = wb2[i2];
            int i0 = 2 * i2, i1 = 2 * i2 + 1;
            int c0 = i0 / 9, r0 = (i0 % 9) / 3, k0 = i0 % 3;
            int c1 = i1 / 9, r1 = (i1 % 9) / 3, k1 = i1 % 3;
            acc += w2.x * pb[(size_t)c0 * P2S + r0 * P2R + k0];
            acc += w2.y * pb[(size_t)c1 * P2S + r1 * P2R + k1];
        }
    }
    acc = acc > THR2 ? acc : 0.f;                        // fire
    colv[t * NLOC + loc] = acc;
}

// ---------- per-loc k-WTA stats from exact columns ----------
__global__ void k_stat(const float* __restrict__ colv, int* __restrict__ nsA,
                       float* __restrict__ vfA, unsigned* __restrict__ vmax) {
    int loc = blockIdx.x * 256 + threadIdx.x;            // 6400 exact
    float col[T_];
    #pragma unroll
    for (int t = 0; t < T_; t++) col[t] = colv[t * NLOC + loc];
    int ns = 0;
    #pragma unroll
    for (int t = 0; t < T_; t++) ns += (col[t] > 0.f);
    int f2 = T_ - ns; if (f2 > T_ - 1) f2 = T_ - 1;
    float vf = 0.f;
    #pragma unroll
    for (int t = 0; t < T_; t++) if (t == f2) vf = col[t];
    nsA[loc] = ns; vfA[loc] = vf;
    atomicMax(vmax, __float_as_uint(vf));
}

// ---------- write-only expansion: spike2 + inhibited pot2 from compact columns ----------
__global__ void k_zero(float* __restrict__ outbuf, const int* __restrict__ winf,
                       const float* __restrict__ colv) {
    int idx = blockIdx.x * 256 + threadIdx.x;
    if (idx >= T_ * F2 * (NLOC / 4)) return;
    int l4 = idx % (NLOC / 4);
    int f  = (idx / (NLOC / 4)) % F2;
    int t  = idx / ((NLOC / 4) * F2);
    int loc = l4 * 4;
    int4   wf = *(const int4*)(winf + loc);
    float4 cv = *(const float4*)(colv + t * NLOC + loc);
    float4 po, sp;
    po.x = (wf.x == f) ? cv.x : 0.f;  sp.x = po.x > 0.f ? 1.f : 0.f;
    po.y = (wf.y == f) ? cv.y : 0.f;  sp.y = po.y > 0.f ? 1.f : 0.f;
    po.z = (wf.z == f) ? cv.z : 0.f;  sp.z = po.z > 0.f ? 1.f : 0.f;
    po.w = (wf.w == f) ? cv.w : 0.f;  sp.w = po.w > 0.f ? 1.f : 0.f;
    size_t off = ((size_t)t * F2 + f) * NLOC + loc;
    *(float4*)(outbuf + POT_OFF + off) = po;
    *(float4*)(outbuf + off) = sp;
}

// ---------- greedy k-WTA; wave-shuffle reduction ----------
__global__ __launch_bounds__(256) void k_winners(const int* __restrict__ winf,
                                                 const int* __restrict__ nsA,
                                                 const float* __restrict__ vfA,
                                                 const unsigned* __restrict__ vmax,
                                                 float* __restrict__ wout) {
    __shared__ float tot[NLOC];
    __shared__ int   wfl[NLOC];
    __shared__ u64   rw[4];
    __shared__ float bvS; __shared__ int fiS, hiS, wiS;
    int tid = threadIdx.x;
    int lane = tid & 63, wv = tid >> 6;
    float v = __uint_as_float(vmax[0]) * (float)T_;
    for (int l = tid; l < NLOC; l += 256) {
        tot[l] = (float)nsA[l] * (vfA[l] + v);           // ns==0 -> 0
        wfl[l] = winf[l];
    }
    __syncthreads();
    for (int it = 0; it < KWTA; it++) {
        float bv = 0.f; int bk = 0x7fffffff;
        #pragma unroll
        for (int i = 0; i < 25; i++) {
            int l = tid * 25 + i;
            float vv = tot[l];
            int k = wfl[l] * NLOC + l;                   // flattened (f,h,w) index
            if (vv > bv || (vv == bv && k < bk)) { bv = vv; bk = k; }
        }
        u64 key = ((u64)__float_as_uint(bv) << 32) | (u64)(unsigned)(0x7fffffff - bk);
        #pragma unroll
        for (int s = 1; s < 64; s <<= 1) {
            u64 o = __shfl_xor(key, s, 64);
            key = key > o ? key : o;
        }
        if (lane == 0) rw[wv] = key;
        __syncthreads();
        if (tid == 0) {
            u64 k0 = rw[0], k1 = rw[1], k2 = rw[2], k3 = rw[3];
            u64 ka = k0 > k1 ? k0 : k1, kb = k2 > k3 ? k2 : k3;
            u64 kk = ka > kb ? ka : kb;
            float bvv = __uint_as_float((unsigned)(kk >> 32));
            int bkk = 0x7fffffff - (int)(kk & 0xFFFFFFFFu);
            bool valid = bvv > 0.f;
            int fi = valid ? bkk / NLOC : -1;
            int lc = bkk % NLOC;
            int hi = valid ? lc / WP : -1;
            int wi = valid ? lc % WP : -1;
            wout[it * 3 + 0] = (float)fi;
            wout[it * 3 + 1] = (float)hi;
            wout[it * 3 + 2] = (float)wi;
            bvS = bvv; fiS = fi; hiS = hi; wiS = wi;
        }
        __syncthreads();
        if (bvS > 0.f) {
            #pragma unroll
            for (int i = 0; i < 25; i++) {
                int l = tid * 25 + i;
                int h = l / WP, w = l % WP;
                bool kill = (wfl[l] == fiS) ||
                            (h >= hiS - 1 && h <= hiS + 1 && w >= wiS - 1 && w <= wiS + 1);
                if (kill) tot[l] = 0.f;
            }
        }
        __syncthreads();
    }
}

extern "C" void kernel_launch(void* const* d_in, const int* in_sizes, int n_in,
                              void* d_out, int out_size, void* d_ws, size_t ws_size,
                              hipStream_t stream) {
    const float* data = (const float*)d_in[0];
    const float* W1   = (const float*)d_in[1];
    const float* W2   = (const float*)d_in[2];
    float* out = (float*)d_out;
    float* ws  = (float*)d_ws;

    // ws layout (floats): P2[3,175,200] Wf2[110,592] Wf1[10,752]
    //   winf[6400] ns[6400] vf[6400] colv[96,000] vmax[1] cnt[1] list[262,144] -> 14.7 MB
    float*    P2   = ws;
    u16*      Wf2  = (u16*)(ws + 3175200);
    u16*      Wf1  = (u16*)(ws + 3285792);
    int*      winf = (int*)(ws + 3296544);
    int*      nsA  = (int*)(ws + 3302944);
    float*    vfA  = ws + 3309344;
    float*    colv = ws + 3315744;
    unsigned* vmax = (unsigned*)(ws + 3411744);
    int*      cnt  = (int*)(ws + 3411745);
    int*      list = (int*)(ws + 3411746);

    // gkey (15 x 6400 u64 = 768 KB) lives in d_out's spike region (rewritten by k_zero)
    u64* gkey = (u64*)d_out;

    k_wprep  <<<948, 256, 0, stream>>>(W2, W1, Wf2, Wf1, P2, vmax, cnt);
    k_conv1m <<<dim3(100, T_), 256, 0, stream>>>(data, Wf1, P2, cnt, list);
    k_fix    <<<2048, 256, 0, stream>>>(data, W1, P2, list, cnt);
    k_conv2m <<<dim3(100, T_), 256, 0, stream>>>(P2, Wf2, gkey);
    k_col    <<<750, 128, 0, stream>>>(gkey, P2, W2, winf, colv);
    k_stat   <<<25, 256, 0, stream>>>(colv, nsA, vfA, vmax);
    k_zero   <<<(T_ * F2 * (NLOC / 4) + 255) / 256, 256, 0, stream>>>(out, winf, colv);
    k_winners<<<1, 256, 0, stream>>>(winf, nsA, vfA, vmax, out + WIN_OFF);
}

// Round 8
// 390.367 us; speedup vs baseline: 1.1991x; 1.0056x over previous
//
#include <hip/hip_runtime.h>
#include <cstdint>

#define T_    15
#define C1    6
#define F1    30
#define THR1  15.0f
#define F2    250
#define THR2  10.0f
#define WP    80
#define NLOC  6400          // 80*80
#define KWTA  8
#define P2R   84
#define P2S   (84*84)       // padded pooled map (pad 1, rounded to 84 for float4 align)
#define POT_OFF 24000000    // d_out: [0,24M) spike2, [24M,48M) pot2, [48M,48M+24) winners
#define WIN_OFF 48000000
#define EPS1  5e-4f         // conv1 decision margin (2.5x pessimistic reorder bound 2e-4)
#define FIXCAP 262144

typedef unsigned long long u64;
typedef unsigned short u16;
typedef short s16x8 __attribute__((ext_vector_type(8)));
typedef float f32x4 __attribute__((ext_vector_type(4)));

static __device__ __forceinline__ u16 f2bf(float x) {      // RNE fp32->bf16
    unsigned u = __float_as_uint(x);
    return (u16)((u + 0x7FFF + ((u >> 16) & 1)) >> 16);
}
static __device__ __forceinline__ float bf2f(u16 h) {
    return __uint_as_float(((unsigned)h) << 16);
}

// ---------- weight prep: bf16x3 splits in MFMA A-frag layout (W2 and W1) ----------
// Wf2 elem E = (((s*9+g)*16 + ft)*64 + lane)*8 + j ; A[m=lane&15][k=(lane>>4)*8+j]
//   f = ft*16 + (lane&15), c = k, g = ky*3+kx. f>=250 / c>=30 zero-padded.
// Wf1 elem E = (((sp*7+s)*2 + ft)*64 + lane)*8 + j
//   f = ft*16 + (lane&15) (<30), kp = s*4 + (lane>>4) = ky*5+kx (<25), c = j (<6).
// Tail: zero P2 border ring + vmax/cnt (replaces hipMemsetAsync launches).
__global__ void k_wprep(const float* __restrict__ W2, const float* __restrict__ W1,
                        u16* __restrict__ Wf2, u16* __restrict__ Wf1,
                        float* __restrict__ P2, unsigned* __restrict__ vmax,
                        int* __restrict__ cnt) {
    int b = blockIdx.x;
    if (b < 864) {
        int E = b * 256 + threadIdx.x;                   // 221,184 exact
        int j    = E & 7;
        int lane = (E >> 3) & 63;
        int ft   = (E >> 9) & 15;
        int rest = E >> 13;                              // 0..26
        int s = rest / 9, g = rest % 9;
        int c = (lane >> 4) * 8 + j;
        int f = ft * 16 + (lane & 15);
        float w = (c < F1 && f < F2) ? W2[f * 270 + c * 9 + g] : 0.f;
        u16 h = f2bf(w);          float fh = bf2f(h);
        u16 m = f2bf(w - fh);     float fm = bf2f(m);
        u16 l = f2bf(w - fh - fm);
        Wf2[E] = (s == 0) ? h : (s == 1) ? m : l;
    } else {
        int E = (b - 864) * 256 + threadIdx.x;           // 21,504 exact
        int j    = E & 7;
        int lane = (E >> 3) & 63;
        int ft   = (E >> 9) & 1;
        int sf   = E >> 10;                              // 0..20
        int s = sf % 7, sp = sf / 7;
        int q = lane >> 4, m15 = lane & 15;
        int f  = ft * 16 + m15;
        int kp = s * 4 + q;
        int c  = j;
        float w = 0.f;
        if (f < F1 && kp < 25 && c < C1) {
            int ky = kp / 5, kx = kp % 5;
            w = W1[((f * C1 + c) * 5 + ky) * 5 + kx];
        }
        u16 h = f2bf(w);          float fh = bf2f(h);
        u16 m = f2bf(w - fh);     float fm = bf2f(m);
        u16 l = f2bf(w - fh - fm);
        Wf1[E] = (sp == 0) ? h : (sp == 1) ? m : l;
    }
    // P2 border ring: rows {0,81,82,83} x all cols + rows 1..80 x cols {0,81,82,83}
    int gtid = b * 256 + threadIdx.x;                    // 242,688 threads
    for (int idx = gtid; idx < 450 * 656; idx += 948 * 256) {
        int map = idx / 656, e = idx % 656;
        int row, col;
        if (e < 336) { int rs = e / 84; row = (rs == 0) ? 0 : 80 + rs; col = e % 84; }
        else { int e2 = e - 336; row = 1 + (e2 >> 2); int cs = e2 & 3; col = (cs == 0) ? 0 : 80 + cs; }
        P2[(size_t)map * P2S + (size_t)row * P2R + col] = 0.f;
    }
    if (gtid == 0) { *vmax = 0u; *cnt = 0; }
}

// ---------- conv1 via MFMA (bf16x3) + fire(15) + 2x2 maxpool + margin flags ----------
// grid (100, 15): block tile = 16 y x 16 x conv outputs, all 32 f (30 real).
// wave wv: conv rows y0+wv*4..+3 (nt), cols x0..x0+15 (n).
// Cells with any |pot-15|<EPS1 are appended to the fixup list (recomputed exactly).
__global__ __launch_bounds__(256) void k_conv1m(const float* __restrict__ data,
                                                const u16* __restrict__ Wf1,
                                                float* __restrict__ P2,
                                                int* __restrict__ cnt,
                                                int* __restrict__ list) {
    __shared__ u16 strip[3200];                          // [20 r][20 col][8 c] bf16
    __shared__ unsigned char pooled[2048];               // [8 py][8 px][32 f]
    int tid  = threadIdx.x;
    int lane = tid & 63;
    int wv   = __builtin_amdgcn_readfirstlane(tid >> 6);
    int t    = blockIdx.y;
    int xt = blockIdx.x % 10, yt = blockIdx.x / 10;
    int x0 = xt * 16, y0 = yt * 16;

    // stage input rows y0-2..y0+17, cols x0-2..x0+17 (bounds-checked virtual pad)
    for (int e = tid; e < 3200; e += 256) {              // e = (c*20 + r)*20 + cl
        int c = e / 400, r = (e / 20) % 20, cl = e % 20;
        int yy = y0 + r - 2, xx = x0 + cl - 2;
        float v = 0.f;
        if (c < C1 && yy >= 0 && yy < 160 && xx >= 0 && xx < 160)
            v = data[(size_t)(t * C1 + c) * 25600 + yy * 160 + xx];
        strip[(r * 20 + cl) * 8 + c] = f2bf(v);
    }
    __syncthreads();

    int q = lane >> 4, n = lane & 15;
    f32x4 acc[2][4];
    #pragma unroll
    for (int j = 0; j < 2; j++)
        #pragma unroll
        for (int nt = 0; nt < 4; nt++) acc[j][nt] = (f32x4)0.f;

    #pragma unroll
    for (int s = 0; s < 7; s++) {
        int kp = s * 4 + q;
        int ky = 0, kx = 0;
        if (kp < 25) { ky = kp / 5; kx = kp - ky * 5; }  // kp>=25: zero weights, read (0,0)
        s16x8 bf[4];
        #pragma unroll
        for (int nt = 0; nt < 4; nt++)
            bf[nt] = *(const s16x8*)&strip[((wv * 4 + nt + ky) * 20 + (n + kx)) * 8];
        #pragma unroll
        for (int sp = 0; sp < 3; sp++) {
            #pragma unroll
            for (int j = 0; j < 2; j++) {
                s16x8 af = *(const s16x8*)&Wf1[(size_t)(((sp * 7 + s) * 2 + j) * 64 + lane) * 8];
                #pragma unroll
                for (int nt = 0; nt < 4; nt++)
                    acc[j][nt] = __builtin_amdgcn_mfma_f32_16x16x32_bf16(af, bf[nt], acc[j][nt], 0, 0, 0);
            }
        }
    }

    // fire + flag; pool x via shfl_xor(1), y via nt pairs; even-n lanes own pooled px
    unsigned sb[4], nf[4];
    #pragma unroll
    for (int nt = 0; nt < 4; nt++) {
        unsigned s8 = 0, fl = 0;
        #pragma unroll
        for (int j = 0; j < 2; j++)
            #pragma unroll
            for (int r = 0; r < 4; r++) {
                float p = acc[j][nt][r];
                s8 |= (p > THR1 ? 1u : 0u) << (j * 4 + r);
                fl |= (fabsf(p - THR1) < EPS1 ? 1u : 0u);
            }
        sb[nt] = s8; nf[nt] = fl;
    }
    #pragma unroll
    for (int nt = 0; nt < 4; nt++) {
        sb[nt] |= (unsigned)__shfl_xor((int)sb[nt], 1, 64);
        nf[nt] |= (unsigned)__shfl_xor((int)nf[nt], 1, 64);
    }
    unsigned p0 = sb[0] | sb[1], p1 = sb[2] | sb[3];
    unsigned fw = (nf[0] | nf[1]) | ((nf[2] | nf[3]) << 1);
    fw |= (unsigned)__shfl_xor((int)fw, 16, 64);         // OR across q groups (dedupe)
    fw |= (unsigned)__shfl_xor((int)fw, 32, 64);
    if (!(n & 1)) {
        int px = n >> 1;
        #pragma unroll
        for (int j = 0; j < 2; j++)
            #pragma unroll
            for (int r = 0; r < 4; r++) {
                int f = j * 16 + q * 4 + r;
                pooled[((wv * 2 + 0) * 8 + px) * 32 + f] = (p0 >> (j * 4 + r)) & 1;
                pooled[((wv * 2 + 1) * 8 + px) * 32 + f] = (p1 >> (j * 4 + r)) & 1;
            }
        if (q == 0 && fw) {                              // one append per flagged cell
            int cb = t * NLOC + (yt * 8) * WP + (xt * 8 + px);
            if (fw & 1) { int id = atomicAdd(cnt, 1); if (id < FIXCAP) list[id] = cb + (wv * 2 + 0) * WP; }
            if (fw & 2) { int id = atomicAdd(cnt, 1); if (id < FIXCAP) list[id] = cb + (wv * 2 + 1) * WP; }
        }
    }
    __syncthreads();
    for (int i = tid; i < 1920; i += 256) {              // 30 f x 8 py x 8 px
        int f = i >> 6, pos = i & 63, py = pos >> 3, px = pos & 7;
        P2[(size_t)(t * F1 + f) * P2S + (size_t)(1 + yt * 8 + py) * P2R + (1 + xt * 8 + px)]
            = pooled[pos * 32 + f] ? 1.f : 0.f;
    }
}

// ---------- exact scalar recompute of flagged pooled cells (fp32 c,ky,kx order) ----------
__global__ void k_fix(const float* __restrict__ data, const float* __restrict__ W1,
                      float* __restrict__ P2, const int* __restrict__ list,
                      const int* __restrict__ cnt) {
    int m = *cnt; if (m > FIXCAP) m = FIXCAP;
    int nitems = m * F1;                                 // thread per (cell, f)
    for (int i = blockIdx.x * 256 + threadIdx.x; i < nitems; i += gridDim.x * 256) {
        int cell = list[i / F1], f = i % F1;
        int t = cell / NLOC, rem = cell % NLOC, py = rem / WP, px = rem % WP;
        bool s = false;
        #pragma unroll
        for (int dy = 0; dy < 2; dy++)
            #pragma unroll
            for (int dx = 0; dx < 2; dx++) {
                int y = 2 * py + dy, x = 2 * px + dx;    // conv output coords
                float acc = 0.f;
                for (int c = 0; c < C1; c++)
                    #pragma unroll
                    for (int ky = 0; ky < 5; ky++)
                        #pragma unroll
                        for (int kx = 0; kx < 5; kx++) {
                            int yy = y + ky - 2, xx = x + kx - 2;
                            float v = (yy >= 0 && yy < 160 && xx >= 0 && xx < 160)
                                ? data[(size_t)(t * C1 + c) * 25600 + yy * 160 + xx] : 0.f;
                            acc += W1[((f * C1 + c) * 5 + ky) * 5 + kx] * v;
                        }
                s |= acc > THR1;
            }
        P2[(size_t)(t * F1 + f) * P2S + (size_t)(1 + py) * P2R + (1 + px)] = s ? 1.f : 0.f;
    }
}

// ---------- conv2 via MFMA (bf16x3, two-bank order) + fire + per-(t,loc) argmax ----------
// grid (100, 15): block tile = 256 f x (4 rows x 16 cols). wave = 64 f x 64 locs.
__global__ __launch_bounds__(256) void k_conv2m(const float* __restrict__ P2,
                                                const u16* __restrict__ Wf,
                                                u64* __restrict__ gkey) {
    __shared__ u16 rawT[3456];                           // [6 r][4 q][18 col][8] bf16
    __shared__ u64 skey[256];                            // [wv][nt][n]
    int tid  = threadIdx.x;
    int lane = tid & 63;
    int wv   = __builtin_amdgcn_readfirstlane(tid >> 6);
    int t    = blockIdx.y;
    int xt = blockIdx.x % 5, yt = blockIdx.x / 5;
    int y0 = yt * 4, x0 = xt * 16;

    // stage strip rows y0..y0+5, cols x0..x0+17, 30ch, vectorized (no bounds: P2 padded)
    for (int e = tid; e < 1116; e += 256) {
        if (e < 900) {
            int pair = e / 5, seg = e - pair * 5;
            int c = pair / 6, r = pair - c * 6;
            const float* src = P2 + (size_t)(t * F1 + c) * P2S + (size_t)(y0 + r) * P2R + x0;
            int base = ((r * 4 + (c >> 3)) * 18) * 8 + (c & 7);
            if (seg < 4) {
                float4 v = *(const float4*)(src + 4 * seg);
                rawT[base + (4 * seg + 0) * 8] = f2bf(v.x);
                rawT[base + (4 * seg + 1) * 8] = f2bf(v.y);
                rawT[base + (4 * seg + 2) * 8] = f2bf(v.z);
                rawT[base + (4 * seg + 3) * 8] = f2bf(v.w);
            } else {
                float2 v = *(const float2*)(src + 16);
                rawT[base + 16 * 8] = f2bf(v.x);
                rawT[base + 17 * 8] = f2bf(v.y);
            }
        } else {
            int e2 = e - 900;                            // 216: c in {30,31} x 6r x 18col
            int c = 30 + e2 / 108, rem = e2 % 108, r = rem / 18, col = rem % 18;
            rawT[((r * 4 + (c >> 3)) * 18 + col) * 8 + (c & 7)] = 0;
        }
    }
    __syncthreads();

    int q = lane >> 4, n = lane & 15;
    f32x4 accA[4][4], accB[4][4];                        // [j(ftile)][nt]: hi | mid+lo
    #pragma unroll
    for (int j = 0; j < 4; j++)
        #pragma unroll
        for (int nt = 0; nt < 4; nt++) { accA[j][nt] = (f32x4)0.f; accB[j][nt] = (f32x4)0.f; }

    #pragma unroll
    for (int ky = 0; ky < 3; ky++) {
        #pragma unroll
        for (int kx = 0; kx < 3; kx++) {
            int g = ky * 3 + kx;
            s16x8 bf[4];
            #pragma unroll
            for (int nt = 0; nt < 4; nt++)
                bf[nt] = *(const s16x8*)&rawT[(((nt + ky) * 4 + q) * 18 + (n + kx)) * 8];
            #pragma unroll
            for (int s = 0; s < 3; s++) {
                #pragma unroll
                for (int j = 0; j < 4; j++) {
                    s16x8 af = *(const s16x8*)&Wf[(size_t)((((s * 9 + g) * 16) + (wv * 4 + j)) * 64 + lane) * 8];
                    if (s == 0) {
                        #pragma unroll
                        for (int nt = 0; nt < 4; nt++)
                            accA[j][nt] = __builtin_amdgcn_mfma_f32_16x16x32_bf16(af, bf[nt], accA[j][nt], 0, 0, 0);
                    } else {
                        #pragma unroll
                        for (int nt = 0; nt < 4; nt++)
                            accB[j][nt] = __builtin_amdgcn_mfma_f32_16x16x32_bf16(af, bf[nt], accB[j][nt], 0, 0, 0);
                    }
                }
            }
        }
    }

    // epilogue: fire + key(val, 255-f), reduce rows/lane, then q-lanes, then waves
    #pragma unroll
    for (int nt = 0; nt < 4; nt++) {
        u64 best = 0;
        #pragma unroll
        for (int j = 0; j < 4; j++) {
            #pragma unroll
            for (int r = 0; r < 4; r++) {
                float pot = accA[j][nt][r] + accB[j][nt][r];
                float rr  = pot > THR2 ? pot : 0.f;
                int f = (wv * 4 + j) * 16 + q * 4 + r;
                u64 key = ((u64)__float_as_uint(rr) << 32) | (u64)(unsigned)(255 - f);
                best = best > key ? best : key;
            }
        }
        u64 o = __shfl_xor(best, 16, 64); best = best > o ? best : o;
        o     = __shfl_xor(best, 32, 64); best = best > o ? best : o;
        if (q == 0) skey[(wv * 4 + nt) * 16 + n] = best;
    }
    __syncthreads();
    if (tid < 64) {
        int nt2 = tid >> 4, n2 = tid & 15;
        u64 bk = skey[nt2 * 16 + n2];
        #pragma unroll
        for (int w = 1; w < 4; w++) {
            u64 k = skey[(w * 4 + nt2) * 16 + n2];
            bk = bk > k ? bk : k;
        }
        gkey[(size_t)t * NLOC + (size_t)(y0 + nt2) * WP + (x0 + n2)] = bk;
    }
}

// ---------- fused: winner logic + exact winner-column recompute + per-loc stats ----------
// block = 256 thr: t = tid/17 (0..14), l = tid%17, loc = blockIdx*17+l. 377 blocks.
// MAC loop bit-identical to R7 k_col (flat c,ky,kx float2). Lanes vary loc fastest
// within a t-group -> pb loads stay coalesced (17x4B segments).
__global__ __launch_bounds__(256) void k_colstat(const u64* __restrict__ gkey,
                                                 const float* __restrict__ P2,
                                                 const float* __restrict__ W2,
                                                 int* __restrict__ winf,
                                                 float* __restrict__ colv,
                                                 int* __restrict__ nsA,
                                                 float* __restrict__ vfA,
                                                 unsigned* __restrict__ vmax) {
    __shared__ int   wfS[17];
    __shared__ float colS[17][15];
    int tid = threadIdx.x;
    int t = tid / 17, l = tid - t * 17;                  // t<15 active (tid<255)
    int loc = blockIdx.x * 17 + l;
    bool act = (t < 15) && (loc < NLOC);

    if (act && t == 0) {
        float mv[T_]; int mi[T_];
        #pragma unroll
        for (int t2 = 0; t2 < T_; t2++) {
            u64 k = gkey[(size_t)t2 * NLOC + loc];
            mv[t2] = __uint_as_float((unsigned)(k >> 32));
            mi[t2] = 255 - (int)(k & 0xFFFFFFFFu);
        }
        int nclamp = 0;
        #pragma unroll
        for (int t2 = 0; t2 < T_; t2++) nclamp += (mv[t2] > 0.f);
        int ft = T_ - nclamp; if (ft > T_ - 1) ft = T_ - 1;
        int wf = -1;
        #pragma unroll
        for (int t2 = 0; t2 < T_; t2++) if (t2 == ft) wf = mi[t2];
        if (!(mv[T_ - 1] > 0.f)) wf = -1;
        winf[loc] = wf;
        wfS[l] = wf;
    }
    __syncthreads();

    if (act) {
        int wf = wfS[l];
        float acc = 0.f;
        if (wf >= 0) {
            int y = loc / WP, x = loc % WP;
            const float*  pb  = P2 + (size_t)(t * F1) * P2S + (size_t)y * P2R + x;
            const float2* wb2 = (const float2*)(W2 + wf * 270);
            #pragma unroll
            for (int i2 = 0; i2 < 135; i2++) {           // i = 2*i2 (+1): flat c,ky,kx
                float2 w2 = wb2[i2];
                int i0 = 2 * i2, i1 = 2 * i2 + 1;
                int c0 = i0 / 9, r0 = (i0 % 9) / 3, k0 = i0 % 3;
                int c1 = i1 / 9, r1 = (i1 % 9) / 3, k1 = i1 % 3;
                acc += w2.x * pb[(size_t)c0 * P2S + r0 * P2R + k0];
                acc += w2.y * pb[(size_t)c1 * P2S + r1 * P2R + k1];
            }
        }
        acc = acc > THR2 ? acc : 0.f;                    // fire
        colv[t * NLOC + loc] = acc;
        colS[l][t] = acc;
    }
    __syncthreads();

    if (act && t == 0) {
        int ns = 0;
        #pragma unroll
        for (int t2 = 0; t2 < T_; t2++) ns += (colS[l][t2] > 0.f);
        int f2 = T_ - ns; if (f2 > T_ - 1) f2 = T_ - 1;
        float vf = 0.f;
        #pragma unroll
        for (int t2 = 0; t2 < T_; t2++) if (t2 == f2) vf = colS[l][t2];
        nsA[loc] = ns; vfA[loc] = vf;
        atomicMax(vmax, __float_as_uint(vf));
    }
}

// ---------- write-only expansion: spike2 + inhibited pot2 (64 B/thread) ----------
__global__ void k_zero(float* __restrict__ outbuf, const int* __restrict__ winf,
                       const float* __restrict__ colv) {
    int idx = blockIdx.x * 256 + threadIdx.x;            // T*F2*800 = 3,000,000 granules
    if (idx >= T_ * F2 * (NLOC / 8)) return;
    int l8 = idx % (NLOC / 8);
    int f  = (idx / (NLOC / 8)) % F2;
    int t  = idx / ((NLOC / 8) * F2);
    int loc = l8 * 8;
    size_t off = ((size_t)t * F2 + f) * NLOC + loc;
    #pragma unroll
    for (int h = 0; h < 2; h++) {
        int4   wf = *(const int4*)(winf + loc + 4 * h);
        float4 cv = *(const float4*)(colv + t * NLOC + loc + 4 * h);
        float4 po, sp;
        po.x = (wf.x == f) ? cv.x : 0.f;  sp.x = po.x > 0.f ? 1.f : 0.f;
        po.y = (wf.y == f) ? cv.y : 0.f;  sp.y = po.y > 0.f ? 1.f : 0.f;
        po.z = (wf.z == f) ? cv.z : 0.f;  sp.z = po.z > 0.f ? 1.f : 0.f;
        po.w = (wf.w == f) ? cv.w : 0.f;  sp.w = po.w > 0.f ? 1.f : 0.f;
        *(float4*)(outbuf + POT_OFF + off + 4 * h) = po;
        *(float4*)(outbuf + off + 4 * h) = sp;
    }
}

// ---------- greedy k-WTA; wave-shuffle reduction ----------
__global__ __launch_bounds__(256) void k_winners(const int* __restrict__ winf,
                                                 const int* __restrict__ nsA,
                                                 const float* __restrict__ vfA,
                                                 const unsigned* __restrict__ vmax,
                                                 float* __restrict__ wout) {
    __shared__ float tot[NLOC];
    __shared__ int   wfl[NLOC];
    __shared__ u64   rw[4];
    __shared__ float bvS; __shared__ int fiS, hiS, wiS;
    int tid = threadIdx.x;
    int lane = tid & 63, wv = tid >> 6;
    float v = __uint_as_float(vmax[0]) * (float)T_;
    for (int l = tid; l < NLOC; l += 256) {
        tot[l] = (float)nsA[l] * (vfA[l] + v);           // ns==0 -> 0
        wfl[l] = winf[l];
    }
    __syncthreads();
    for (int it = 0; it < KWTA; it++) {
        float bv = 0.f; int bk = 0x7fffffff;
        #pragma unroll
        for (int i = 0; i < 25; i++) {
            int l = tid * 25 + i;
            float vv = tot[l];
            int k = wfl[l] * NLOC + l;                   // flattened (f,h,w) index
            if (vv > bv || (vv == bv && k < bk)) { bv = vv; bk = k; }
        }
        u64 key = ((u64)__float_as_uint(bv) << 32) | (u64)(unsigned)(0x7fffffff - bk);
        #pragma unroll
        for (int s = 1; s < 64; s <<= 1) {
            u64 o = __shfl_xor(key, s, 64);
            key = key > o ? key : o;
        }
        if (lane == 0) rw[wv] = key;
        __syncthreads();
        if (tid == 0) {
            u64 k0 = rw[0], k1 = rw[1], k2 = rw[2], k3 = rw[3];
            u64 ka = k0 > k1 ? k0 : k1, kb = k2 > k3 ? k2 : k3;
            u64 kk = ka > kb ? ka : kb;
            float bvv = __uint_as_float((unsigned)(kk >> 32));
            int bkk = 0x7fffffff - (int)(kk & 0xFFFFFFFFu);
            bool valid = bvv > 0.f;
            int fi = valid ? bkk / NLOC : -1;
            int lc = bkk % NLOC;
            int hi = valid ? lc / WP : -1;
            int wi = valid ? lc % WP : -1;
            wout[it * 3 + 0] = (float)fi;
            wout[it * 3 + 1] = (float)hi;
            wout[it * 3 + 2] = (float)wi;
            bvS = bvv; fiS = fi; hiS = hi; wiS = wi;
        }
        __syncthreads();
        if (bvS > 0.f) {
            #pragma unroll
            for (int i = 0; i < 25; i++) {
                int l = tid * 25 + i;
                int h = l / WP, w = l % WP;
                bool kill = (wfl[l] == fiS) ||
                            (h >= hiS - 1 && h <= hiS + 1 && w >= wiS - 1 && w <= wiS + 1);
                if (kill) tot[l] = 0.f;
            }
        }
        __syncthreads();
    }
}

extern "C" void kernel_launch(void* const* d_in, const int* in_sizes, int n_in,
                              void* d_out, int out_size, void* d_ws, size_t ws_size,
                              hipStream_t stream) {
    const float* data = (const float*)d_in[0];
    const float* W1   = (const float*)d_in[1];
    const float* W2   = (const float*)d_in[2];
    float* out = (float*)d_out;
    float* ws  = (float*)d_ws;

    // ws layout (floats): P2[3,175,200] Wf2[110,592] Wf1[10,752]
    //   winf[6400] ns[6400] vf[6400] colv[96,000] vmax[1] cnt[1] list[262,144] -> 14.7 MB
    float*    P2   = ws;
    u16*      Wf2  = (u16*)(ws + 3175200);
    u16*      Wf1  = (u16*)(ws + 3285792);
    int*      winf = (int*)(ws + 3296544);
    int*      nsA  = (int*)(ws + 3302944);
    float*    vfA  = ws + 3309344;
    float*    colv = ws + 3315744;
    unsigned* vmax = (unsigned*)(ws + 3411744);
    int*      cnt  = (int*)(ws + 3411745);
    int*      list = (int*)(ws + 3411746);

    // gkey (15 x 6400 u64 = 768 KB) lives in d_out's spike region (rewritten by k_zero)
    u64* gkey = (u64*)d_out;

    k_wprep  <<<948, 256, 0, stream>>>(W2, W1, Wf2, Wf1, P2, vmax, cnt);
    k_conv1m <<<dim3(100, T_), 256, 0, stream>>>(data, Wf1, P2, cnt, list);
    k_fix    <<<2048, 256, 0, stream>>>(data, W1, P2, list, cnt);
    k_conv2m <<<dim3(100, T_), 256, 0, stream>>>(P2, Wf2, gkey);
    k_colstat<<<377, 256, 0, stream>>>(gkey, P2, W2, winf, colv, nsA, vfA, vmax);
    k_zero   <<<(T_ * F2 * (NLOC / 8) + 255) / 256, 256, 0, stream>>>(out, winf, colv);
    k_winners<<<1, 256, 0, stream>>>(winf, nsA, vfA, vmax, out + WIN_OFF);
}